// Round 3
// baseline (3407.928 us; speedup 1.0000x reference)
//
#include <hip/hip_runtime.h>
#include <hip/hip_bf16.h>

// 2-layer GCN encoder: (GCNConv -> BatchNorm1d(train) -> PReLU) x 2
// N=50000, E=800000, D=128. Reference dtypes f32 / int64. Evidence so far:
// inputs are f32 (round-1 bf16 read -> NaN), output is f32 (round-2 bf16
// write -> full-scale garbage). We still probe dtypes on-device and branch
// uniformly, so either layout works. Internal math f32.
//
// ws layout:
//   [0 .. 200000)            dinv (f32, per node)  -- deg then rsqrt in place
//   [200704 .. +8)           flags: [0]=int64?, [1]=bf16-floats?
//   [201728 .. +1024)        BN stats (sum[128], sumsq[128])
//   [1048576 .. +25.6MB)     bufA (f32 N x 128)
//   [26648576 .. +25.6MB)    bufB (f32 N x 128)
// total ~52.3 MB

typedef __hip_bfloat16 bf16;

#define NN 50000
#define NE 800000
#define DD 128
#define BN_EPS 1e-5f

__device__ __forceinline__ float b2f(bf16 v) { return __bfloat162float(v); }
// load element idx from a float array that may be bf16 or f32
__device__ __forceinline__ float ldf(const void* p, size_t idx, int isbf) {
  return isbf ? b2f(((const bf16*)p)[idx]) : ((const float*)p)[idx];
}
__device__ __forceinline__ int lde(const void* ei, size_t idx, int is64) {
  return is64 ? (int)((const long long*)ei)[idx] : ((const int*)ei)[idx];
}

// 64 threads. flags[0]: int64 edge_index?  flags[1]: bf16 floats?
__global__ void k_detect(const int* ei, const unsigned short* x16, int* flags) {
  int t = threadIdx.x;
  // int64 probe: for int64 (values < 2^31, LE), every odd 32-bit word is 0.
  unsigned long long m1 = __ballot(ei[2 * t + 1] != 0);
  // bf16 probe: even half-words. bf16 -> real ~N(0,1) elements, exponent field
  // in [90,140] essentially always. f32 -> uniform mantissa bits, ~20% in-window.
  int ex = (x16[2 * t] >> 7) & 0xFF;
  unsigned long long m2 = __ballot(ex >= 90 && ex <= 140);
  if (t == 0) {
    flags[0] = (m1 == 0ull) ? 1 : 0;
    flags[1] = (__popcll(m2) >= 48) ? 1 : 0;
  }
}

__global__ __launch_bounds__(256) void k_init_deg(float* deg) {
  int i = blockIdx.x * 256 + threadIdx.x;
  if (i < NN) deg[i] = 1.0f;  // self-loop
}

__global__ __launch_bounds__(256) void k_count_deg(const void* ei, const int* flags, float* deg) {
  int e = blockIdx.x * 256 + threadIdx.x;
  if (e >= NE) return;
  int d = lde(ei, (size_t)NE + e, flags[0]);
  atomicAdd(&deg[d], 1.0f);
}

__global__ __launch_bounds__(256) void k_dinv(float* deg) {
  int i = blockIdx.x * 256 + threadIdx.x;
  if (i < NN) deg[i] = rsqrtf(deg[i]);
}

// out[N,128] = in[N,128] @ W[128,128]. W staged to LDS as f32 (single compute
// path for bf16/f32 sources). 64 rows/block, 4-row register accumulators.
// XMAYBE: x may be bf16 (layer 1, raw input); layer 2 input is internal f32.
template <bool XMAYBE>
__global__ __launch_bounds__(128) void k_gemm(const void* in_, const void* W,
                                              const int* flags, float* out) {
  __shared__ float sW[DD * DD];  // 64 KB
  __shared__ float sx[4 * DD];   // 2 KB
  const int isbf = flags[1];
  const int isx = XMAYBE ? isbf : 0;
  const int j = threadIdx.x;
  for (int idx = j; idx < DD * DD; idx += 128) sW[idx] = ldf(W, idx, isbf);
  const int row0 = blockIdx.x * 64;
  for (int rb = 0; rb < 64; rb += 4) {
    const int r0 = row0 + rb;
    __syncthreads();  // covers sW load (first iter) and prev-iter sx reads
#pragma unroll
    for (int t = 0; t < 4; t++) {
      const int row = r0 + t;
      sx[t * DD + j] = (row < NN) ? ldf(in_, (size_t)row * DD + j, isx) : 0.f;
    }
    __syncthreads();
    float a0 = 0.f, a1 = 0.f, a2 = 0.f, a3 = 0.f;
#pragma unroll 8
    for (int k = 0; k < DD; k++) {
      const float w = sW[k * DD + j];
      a0 += sx[0 * DD + k] * w;
      a1 += sx[1 * DD + k] * w;
      a2 += sx[2 * DD + k] * w;
      a3 += sx[3 * DD + k] * w;
    }
    if (r0 + 0 < NN) out[(size_t)(r0 + 0) * DD + j] = a0;
    if (r0 + 1 < NN) out[(size_t)(r0 + 1) * DD + j] = a1;
    if (r0 + 2 < NN) out[(size_t)(r0 + 2) * DD + j] = a2;
    if (r0 + 3 < NN) out[(size_t)(r0 + 3) * DD + j] = a3;
  }
}

// agg[i,:] = dinv[i]^2 * h[i,:] + b[:]   (self-loop term + bias; full overwrite)
__global__ __launch_bounds__(256) void k_agg_init(const float* h, const float* dinv,
                                                  const void* b, const int* flags, float* agg) {
  int i4 = blockIdx.x * 256 + threadIdx.x;  // over NN*32 float4s
  if (i4 >= NN * 32) return;
  int isbf = flags[1];
  int node = i4 >> 5;
  int jq = (i4 & 31) * 4;
  float di = dinv[node];
  float c = di * di;
  const float4 hv = ((const float4*)h)[i4];
  float4 o;
  o.x = c * hv.x + ldf(b, jq + 0, isbf);
  o.y = c * hv.y + ldf(b, jq + 1, isbf);
  o.z = c * hv.z + ldf(b, jq + 2, isbf);
  o.w = c * hv.w + ldf(b, jq + 3, isbf);
  ((float4*)agg)[i4] = o;
}

// agg[dst,:] += dinv[src]*dinv[dst] * h[src,:]   (32 threads/edge, float4 gather)
__global__ __launch_bounds__(256) void k_scatter(const void* ei, const int* flags,
                                                 const float* dinv, const float* h, float* agg) {
  int t = blockIdx.x * 256 + threadIdx.x;
  int e = t >> 5;
  if (e >= NE) return;
  int lane = t & 31;
  int is64 = flags[0];
  int s = lde(ei, e, is64);
  int d = lde(ei, (size_t)NE + e, is64);
  float c = dinv[s] * dinv[d];
  const float4 hv = ((const float4*)(h + (size_t)s * DD))[lane];
  float* ap = agg + (size_t)d * DD + lane * 4;
  atomicAdd(ap + 0, c * hv.x);
  atomicAdd(ap + 1, c * hv.y);
  atomicAdd(ap + 2, c * hv.z);
  atomicAdd(ap + 3, c * hv.w);
}

__global__ void k_zero_stats(float* stats) { stats[threadIdx.x] = 0.f; }  // 256 threads

__global__ __launch_bounds__(128) void k_bn_stats(const float* x, float* stats) {
  int j = threadIdx.x;
  float s = 0.f, q = 0.f;
  for (int r = blockIdx.x; r < NN; r += gridDim.x) {
    float v = x[(size_t)r * DD + j];
    s += v;
    q += v * v;
  }
  atomicAdd(&stats[j], s);
  atomicAdd(&stats[DD + j], q);
}

// FINAL: last layer writes d_out. Output dtype follows the (probed) float
// dtype of the inputs: f32 inputs -> f32 out, bf16 inputs -> bf16 out.
template <bool FINAL>
__global__ __launch_bounds__(256) void k_bn_apply(const float* x, const float* stats,
                                                  const void* g, const void* be, const void* al,
                                                  const int* flags, void* out) {
  int i4 = blockIdx.x * 256 + threadIdx.x;  // over NN*32 float4s
  if (i4 >= NN * 32) return;
  int isbf = flags[1];
  int jq = (i4 & 31) * 4;
  const float inv_n = 1.0f / NN;
  float alpha = ldf(al, 0, isbf);
  const float4 xv = ((const float4*)x)[i4];
  float xa[4] = {xv.x, xv.y, xv.z, xv.w};
  float y[4];
#pragma unroll
  for (int u = 0; u < 4; u++) {
    int j = jq + u;
    float mu = stats[j] * inv_n;
    float var = stats[DD + j] * inv_n - mu * mu;
    float sc = rsqrtf(var + BN_EPS) * ldf(g, j, isbf);
    float v = (xa[u] - mu) * sc + ldf(be, j, isbf);
    y[u] = v > 0.f ? v : alpha * v;
  }
  if (FINAL && isbf) {
    bf16* o = (bf16*)out;
#pragma unroll
    for (int u = 0; u < 4; u++) o[(size_t)i4 * 4 + u] = __float2bfloat16(y[u]);
  } else {
    float4 o = {y[0], y[1], y[2], y[3]};
    ((float4*)out)[i4] = o;
  }
}

extern "C" void kernel_launch(void* const* d_in, const int* in_sizes, int n_in,
                              void* d_out, int out_size, void* d_ws, size_t ws_size,
                              hipStream_t stream) {
  const void* x = d_in[0];
  const void* ei = d_in[1];
  const void* W1 = d_in[2];
  const void* b1 = d_in[3];
  const void* g1 = d_in[4];
  const void* be1 = d_in[5];
  const void* a1 = d_in[6];
  const void* W2 = d_in[7];
  const void* b2 = d_in[8];
  const void* g2 = d_in[9];
  const void* be2 = d_in[10];
  const void* a2 = d_in[11];

  char* w = (char*)d_ws;
  float* dinv = (float*)w;                          // 200000 B
  int* flags = (int*)(w + 200704);                  // 8 B
  float* stats = (float*)(w + 201728);              // 1024 B
  float* bufA = (float*)(w + 1048576);              // 25.6 MB
  float* bufB = (float*)(w + 1048576 + 25600000);   // 25.6 MB (16B aligned)

  const int NB_N = (NN + 255) / 256;       // 196
  const int NB_E = (NE + 255) / 256;       // 3125
  const int NB_G = (NN + 63) / 64;         // 782 gemm blocks
  const int NB_V = NN * 32 / 256;          // 6250 (exact)
  const int NB_S = NE * 32 / 256;          // 100000 (exact)

  k_detect<<<dim3(1), dim3(64), 0, stream>>>((const int*)ei, (const unsigned short*)x, flags);

  // degrees (dst-only => shared by both layers)
  k_init_deg<<<dim3(NB_N), dim3(256), 0, stream>>>(dinv);
  k_count_deg<<<dim3(NB_E), dim3(256), 0, stream>>>(ei, flags, dinv);
  k_dinv<<<dim3(NB_N), dim3(256), 0, stream>>>(dinv);

  // ---- layer 1 ----
  k_gemm<true><<<dim3(NB_G), dim3(128), 0, stream>>>(x, W1, flags, bufA);
  k_agg_init<<<dim3(NB_V), dim3(256), 0, stream>>>(bufA, dinv, b1, flags, bufB);
  k_scatter<<<dim3(NB_S), dim3(256), 0, stream>>>(ei, flags, dinv, bufA, bufB);
  k_zero_stats<<<dim3(1), dim3(256), 0, stream>>>(stats);
  k_bn_stats<<<dim3(256), dim3(128), 0, stream>>>(bufB, stats);
  k_bn_apply<false><<<dim3(NB_V), dim3(256), 0, stream>>>(bufB, stats, g1, be1, a1, flags, bufA);

  // ---- layer 2 ----
  k_gemm<false><<<dim3(NB_G), dim3(128), 0, stream>>>(bufA, W2, flags, bufB);
  k_agg_init<<<dim3(NB_V), dim3(256), 0, stream>>>(bufB, dinv, b2, flags, bufA);
  k_scatter<<<dim3(NB_S), dim3(256), 0, stream>>>(ei, flags, dinv, bufB, bufA);
  k_zero_stats<<<dim3(1), dim3(256), 0, stream>>>(stats);
  k_bn_stats<<<dim3(256), dim3(128), 0, stream>>>(bufA, stats);
  k_bn_apply<true><<<dim3(NB_V), dim3(256), 0, stream>>>(bufA, stats, g2, be2, a2, flags, d_out);
}

// Round 4
// 979.694 us; speedup vs baseline: 3.4786x; 3.4786x over previous
//
#include <hip/hip_runtime.h>
#include <hip/hip_bf16.h>

// 2-layer GCN encoder: (GCNConv -> BatchNorm1d(train) -> PReLU) x 2
// N=50000, E=800000, D=128. Inputs f32 (probed), edge_index int64 (probed),
// output f32. Internal math f32.
//
// R4: replace f32-atomic scatter (2x1350us, 16B TCC RMW per 4B atomic) with a
// dst-sorted CSR built once (int degree count -> LDS scan -> bucket fill) and
// a register-accumulating one-wave-per-node gather kernel. No f32 atomics.
//
// ws layout (bytes):
//   [0       .. +200000)   dinv f32[NN]
//   [200704  .. +8)        flags: [0]=int64?, [1]=bf16-floats?
//   [201728  .. +1024)     BN stats (sum[128], sumsq[128])
//   [204800  .. +200000)   deg   int[NN]
//   [404800  .. +200004)   rowptr int[NN+1]
//   [604816  .. +200000)   fill  int[NN]
//   [1048576 .. +3.2MB)    csr_src int[NE]
//   [4456448 .. +25.6MB)   bufA f32[NN*DD]
//   [30056448.. +25.6MB)   bufB f32[NN*DD]
// total ~55.7 MB

typedef __hip_bfloat16 bf16;

#define NN 50000
#define NE 800000
#define DD 128
#define BN_EPS 1e-5f

__device__ __forceinline__ float b2f(bf16 v) { return __bfloat162float(v); }
__device__ __forceinline__ float ldf(const void* p, size_t idx, int isbf) {
  return isbf ? b2f(((const bf16*)p)[idx]) : ((const float*)p)[idx];
}
__device__ __forceinline__ int lde(const void* ei, size_t idx, int is64) {
  return is64 ? (int)((const long long*)ei)[idx] : ((const int*)ei)[idx];
}

// 64 threads. flags[0]: int64 edge_index?  flags[1]: bf16 floats?
__global__ void k_detect(const int* ei, const unsigned short* x16, int* flags) {
  int t = threadIdx.x;
  unsigned long long m1 = __ballot(ei[2 * t + 1] != 0);
  int ex = (x16[2 * t] >> 7) & 0xFF;
  unsigned long long m2 = __ballot(ex >= 90 && ex <= 140);
  if (t == 0) {
    flags[0] = (m1 == 0ull) ? 1 : 0;
    flags[1] = (__popcll(m2) >= 48) ? 1 : 0;
  }
}

__global__ __launch_bounds__(256) void k_zero_deg(int* deg) {
  int i = blockIdx.x * 256 + threadIdx.x;
  if (i < NN) deg[i] = 0;
}

__global__ __launch_bounds__(256) void k_count_deg(const void* ei, const int* flags, int* deg) {
  int e = blockIdx.x * 256 + threadIdx.x;
  if (e >= NE) return;
  int d = lde(ei, (size_t)NE + e, flags[0]);
  atomicAdd(&deg[d], 1);
}

__global__ __launch_bounds__(256) void k_dinv(const int* deg, float* dinv) {
  int i = blockIdx.x * 256 + threadIdx.x;
  if (i < NN) dinv[i] = rsqrtf((float)(deg[i] + 1));  // +1 self-loop
}

// Exclusive prefix scan of deg[NN] -> rowptr[NN+1]. Single block, 1024 thr.
__global__ __launch_bounds__(1024) void k_scan(const int* deg, int* rowptr) {
  __shared__ int s[1024];
  __shared__ int carry;
  if (threadIdx.x == 0) carry = 0;
  __syncthreads();
  for (int base = 0; base < NN; base += 1024) {
    int i = base + threadIdx.x;
    int v = (i < NN) ? deg[i] : 0;
    s[threadIdx.x] = v;
    __syncthreads();
    for (int off = 1; off < 1024; off <<= 1) {
      int t = (threadIdx.x >= off) ? s[threadIdx.x - off] : 0;
      __syncthreads();
      s[threadIdx.x] += t;
      __syncthreads();
    }
    if (i < NN) rowptr[i] = carry + s[threadIdx.x] - v;  // exclusive
    __syncthreads();
    if (threadIdx.x == 1023) carry += s[1023];
    __syncthreads();
  }
  if (threadIdx.x == 0) rowptr[NN] = carry;  // == NE
}

__global__ __launch_bounds__(256) void k_copy_fill(const int* rowptr, int* fill) {
  int i = blockIdx.x * 256 + threadIdx.x;
  if (i < NN) fill[i] = rowptr[i];
}

__global__ __launch_bounds__(256) void k_fill(const void* ei, const int* flags,
                                              int* fill, int* csr_src) {
  int e = blockIdx.x * 256 + threadIdx.x;
  if (e >= NE) return;
  int is64 = flags[0];
  int s = lde(ei, e, is64);
  int d = lde(ei, (size_t)NE + e, is64);
  int pos = atomicAdd(&fill[d], 1);
  csr_src[pos] = s;
}

// out[N,128] = in[N,128] @ W[128,128]. W staged to LDS as f32.
template <bool XMAYBE>
__global__ __launch_bounds__(128) void k_gemm(const void* in_, const void* W,
                                              const int* flags, float* out) {
  __shared__ float sW[DD * DD];  // 64 KB
  __shared__ float sx[4 * DD];
  const int isbf = flags[1];
  const int isx = XMAYBE ? isbf : 0;
  const int j = threadIdx.x;
  for (int idx = j; idx < DD * DD; idx += 128) sW[idx] = ldf(W, idx, isbf);
  const int row0 = blockIdx.x * 64;
  for (int rb = 0; rb < 64; rb += 4) {
    const int r0 = row0 + rb;
    __syncthreads();
#pragma unroll
    for (int t = 0; t < 4; t++) {
      const int row = r0 + t;
      sx[t * DD + j] = (row < NN) ? ldf(in_, (size_t)row * DD + j, isx) : 0.f;
    }
    __syncthreads();
    float a0 = 0.f, a1 = 0.f, a2 = 0.f, a3 = 0.f;
#pragma unroll 8
    for (int k = 0; k < DD; k++) {
      const float w = sW[k * DD + j];
      a0 += sx[0 * DD + k] * w;
      a1 += sx[1 * DD + k] * w;
      a2 += sx[2 * DD + k] * w;
      a3 += sx[3 * DD + k] * w;
    }
    if (r0 + 0 < NN) out[(size_t)(r0 + 0) * DD + j] = a0;
    if (r0 + 1 < NN) out[(size_t)(r0 + 1) * DD + j] = a1;
    if (r0 + 2 < NN) out[(size_t)(r0 + 2) * DD + j] = a2;
    if (r0 + 3 < NN) out[(size_t)(r0 + 3) * DD + j] = a3;
  }
}

// One wave per node d: agg[d] = dinv[d]*(dinv[d]*h[d] + sum_e dinv[s]*h[s]) + b
// Lane owns 2 columns (float2). Register accumulation; one coalesced write.
__global__ __launch_bounds__(256) void k_agg(const float* h, const float* dinv,
                                             const int* rowptr, const int* csr_src,
                                             const void* bias, const int* flags, float* out) {
  int w = (blockIdx.x * 256 + threadIdx.x) >> 6;
  if (w >= NN) return;
  int lane = threadIdx.x & 63;
  const float2* h2 = (const float2*)h;
  float dd_ = dinv[w];
  float2 hv = h2[(size_t)w * 64 + lane];
  float ax = dd_ * hv.x, ay = dd_ * hv.y;
  int e = rowptr[w], e1 = rowptr[w + 1];
  for (; e + 1 < e1; e += 2) {  // 2-edge unroll: two row-loads in flight
    int s0 = csr_src[e], s1 = csr_src[e + 1];
    float c0 = dinv[s0], c1 = dinv[s1];
    float2 v0 = h2[(size_t)s0 * 64 + lane];
    float2 v1 = h2[(size_t)s1 * 64 + lane];
    ax += c0 * v0.x + c1 * v1.x;
    ay += c0 * v0.y + c1 * v1.y;
  }
  if (e < e1) {
    int s0 = csr_src[e];
    float c0 = dinv[s0];
    float2 v0 = h2[(size_t)s0 * 64 + lane];
    ax += c0 * v0.x;
    ay += c0 * v0.y;
  }
  int isbf = flags[1];
  float2 o;
  o.x = dd_ * ax + ldf(bias, 2 * lane + 0, isbf);
  o.y = dd_ * ay + ldf(bias, 2 * lane + 1, isbf);
  ((float2*)out)[(size_t)w * 64 + lane] = o;
}

__global__ void k_zero_stats(float* stats) { stats[threadIdx.x] = 0.f; }  // 256 thr

__global__ __launch_bounds__(128) void k_bn_stats(const float* x, float* stats) {
  int j = threadIdx.x;
  float s = 0.f, q = 0.f;
  for (int r = blockIdx.x; r < NN; r += gridDim.x) {
    float v = x[(size_t)r * DD + j];
    s += v;
    q += v * v;
  }
  atomicAdd(&stats[j], s);
  atomicAdd(&stats[DD + j], q);
}

// FINAL && bf16-inputs -> bf16 out; else f32 out.
template <bool FINAL>
__global__ __launch_bounds__(256) void k_bn_apply(const float* x, const float* stats,
                                                  const void* g, const void* be, const void* al,
                                                  const int* flags, void* out) {
  int i4 = blockIdx.x * 256 + threadIdx.x;
  if (i4 >= NN * 32) return;
  int isbf = flags[1];
  int jq = (i4 & 31) * 4;
  const float inv_n = 1.0f / NN;
  float alpha = ldf(al, 0, isbf);
  const float4 xv = ((const float4*)x)[i4];
  float xa[4] = {xv.x, xv.y, xv.z, xv.w};
  float y[4];
#pragma unroll
  for (int u = 0; u < 4; u++) {
    int j = jq + u;
    float mu = stats[j] * inv_n;
    float var = stats[DD + j] * inv_n - mu * mu;
    float sc = rsqrtf(var + BN_EPS) * ldf(g, j, isbf);
    float v = (xa[u] - mu) * sc + ldf(be, j, isbf);
    y[u] = v > 0.f ? v : alpha * v;
  }
  if (FINAL && isbf) {
    bf16* o = (bf16*)out;
#pragma unroll
    for (int u = 0; u < 4; u++) o[(size_t)i4 * 4 + u] = __float2bfloat16(y[u]);
  } else {
    float4 o = {y[0], y[1], y[2], y[3]};
    ((float4*)out)[i4] = o;
  }
}

extern "C" void kernel_launch(void* const* d_in, const int* in_sizes, int n_in,
                              void* d_out, int out_size, void* d_ws, size_t ws_size,
                              hipStream_t stream) {
  const void* x = d_in[0];
  const void* ei = d_in[1];
  const void* W1 = d_in[2];
  const void* b1 = d_in[3];
  const void* g1 = d_in[4];
  const void* be1 = d_in[5];
  const void* a1 = d_in[6];
  const void* W2 = d_in[7];
  const void* b2 = d_in[8];
  const void* g2 = d_in[9];
  const void* be2 = d_in[10];
  const void* a2 = d_in[11];

  char* w = (char*)d_ws;
  float* dinv = (float*)w;                       // 200000
  int* flags = (int*)(w + 200704);               // 8
  float* stats = (float*)(w + 201728);           // 1024
  int* deg = (int*)(w + 204800);                 // 200000
  int* rowptr = (int*)(w + 404800);              // 200004
  int* fill = (int*)(w + 604816);                // 200000
  int* csr_src = (int*)(w + 1048576);            // 3200000
  float* bufA = (float*)(w + 4456448);           // 25600000
  float* bufB = (float*)(w + 30056448);          // 25600000

  const int NB_N = (NN + 255) / 256;   // 196
  const int NB_E = (NE + 255) / 256;   // 3125
  const int NB_G = (NN + 63) / 64;     // 782
  const int NB_V = NN * 32 / 256;      // 6250 (exact)
  const int NB_W = NN * 64 / 256;      // 12500 (exact) one wave per node

  k_detect<<<dim3(1), dim3(64), 0, stream>>>((const int*)ei, (const unsigned short*)x, flags);

  // CSR build (shared by both layers) + dinv
  k_zero_deg<<<dim3(NB_N), dim3(256), 0, stream>>>(deg);
  k_count_deg<<<dim3(NB_E), dim3(256), 0, stream>>>(ei, flags, deg);
  k_dinv<<<dim3(NB_N), dim3(256), 0, stream>>>(deg, dinv);
  k_scan<<<dim3(1), dim3(1024), 0, stream>>>(deg, rowptr);
  k_copy_fill<<<dim3(NB_N), dim3(256), 0, stream>>>(rowptr, fill);
  k_fill<<<dim3(NB_E), dim3(256), 0, stream>>>(ei, flags, fill, csr_src);

  // ---- layer 1 ----
  k_gemm<true><<<dim3(NB_G), dim3(128), 0, stream>>>(x, W1, flags, bufA);
  k_agg<<<dim3(NB_W), dim3(256), 0, stream>>>(bufA, dinv, rowptr, csr_src, b1, flags, bufB);
  k_zero_stats<<<dim3(1), dim3(256), 0, stream>>>(stats);
  k_bn_stats<<<dim3(256), dim3(128), 0, stream>>>(bufB, stats);
  k_bn_apply<false><<<dim3(NB_V), dim3(256), 0, stream>>>(bufB, stats, g1, be1, a1, flags, bufA);

  // ---- layer 2 ----
  k_gemm<false><<<dim3(NB_G), dim3(128), 0, stream>>>(bufA, W2, flags, bufB);
  k_agg<<<dim3(NB_W), dim3(256), 0, stream>>>(bufB, dinv, rowptr, csr_src, b2, flags, bufA);
  k_zero_stats<<<dim3(1), dim3(256), 0, stream>>>(stats);
  k_bn_stats<<<dim3(256), dim3(128), 0, stream>>>(bufA, stats);
  k_bn_apply<true><<<dim3(NB_V), dim3(256), 0, stream>>>(bufA, stats, g2, be2, a2, flags, d_out);
}

// Round 5
// 643.911 us; speedup vs baseline: 5.2925x; 1.5215x over previous
//
#include <hip/hip_runtime.h>
#include <hip/hip_bf16.h>

// 2-layer GCN encoder: (GCNConv -> BatchNorm1d(train) -> PReLU) x 2
// N=50000, E=800000, D=128. Inputs f32 (probed), edge_index int64 (probed),
// output f32. Internal math f32 except GEMM inputs cast to bf16 for MFMA.
//
// R5: k_gemm (vector f32, 7.5 TF, MfmaUtil=0) -> v_mfma_f32_16x16x32_bf16.
// W staged to LDS in fragment-contiguous layout sW[c][n][j]=W[8c+j][n] so a
// B-fragment is one ds_read_b128; A-frags loaded from global + cvt to bf16.
//
// ws layout (bytes):
//   [0       .. +200000)   dinv f32[NN]
//   [200704  .. +8)        flags: [0]=int64?, [1]=bf16-floats?
//   [201728  .. +1024)     BN stats (sum[128], sumsq[128])
//   [204800  .. +200000)   deg   int[NN]
//   [404800  .. +200004)   rowptr int[NN+1]
//   [604816  .. +200000)   fill  int[NN]
//   [1048576 .. +3.2MB)    csr_src int[NE]
//   [4456448 .. +25.6MB)   bufA f32[NN*DD]
//   [30056448.. +25.6MB)   bufB f32[NN*DD]
// total ~55.7 MB

typedef __hip_bfloat16 bf16;
typedef __attribute__((ext_vector_type(8))) short short8;   // 8 bf16 = 4 VGPR
typedef __attribute__((ext_vector_type(4))) float f32x4;    // MFMA accumulator

#define NN 50000
#define NE 800000
#define DD 128
#define BN_EPS 1e-5f

__device__ __forceinline__ float b2f(bf16 v) { return __bfloat162float(v); }
__device__ __forceinline__ float ldf(const void* p, size_t idx, int isbf) {
  return isbf ? b2f(((const bf16*)p)[idx]) : ((const float*)p)[idx];
}
__device__ __forceinline__ int lde(const void* ei, size_t idx, int is64) {
  return is64 ? (int)((const long long*)ei)[idx] : ((const int*)ei)[idx];
}
__device__ __forceinline__ short f2bs(float v) {
  bf16 b = __float2bfloat16(v);
  return *reinterpret_cast<short*>(&b);
}

// 64 threads. flags[0]: int64 edge_index?  flags[1]: bf16 floats?
__global__ void k_detect(const int* ei, const unsigned short* x16, int* flags) {
  int t = threadIdx.x;
  unsigned long long m1 = __ballot(ei[2 * t + 1] != 0);
  int ex = (x16[2 * t] >> 7) & 0xFF;
  unsigned long long m2 = __ballot(ex >= 90 && ex <= 140);
  if (t == 0) {
    flags[0] = (m1 == 0ull) ? 1 : 0;
    flags[1] = (__popcll(m2) >= 48) ? 1 : 0;
  }
}

__global__ __launch_bounds__(256) void k_zero_deg(int* deg) {
  int i = blockIdx.x * 256 + threadIdx.x;
  if (i < NN) deg[i] = 0;
}

__global__ __launch_bounds__(256) void k_count_deg(const void* ei, const int* flags, int* deg) {
  int e = blockIdx.x * 256 + threadIdx.x;
  if (e >= NE) return;
  int d = lde(ei, (size_t)NE + e, flags[0]);
  atomicAdd(&deg[d], 1);
}

__global__ __launch_bounds__(256) void k_dinv(const int* deg, float* dinv) {
  int i = blockIdx.x * 256 + threadIdx.x;
  if (i < NN) dinv[i] = rsqrtf((float)(deg[i] + 1));  // +1 self-loop
}

// Exclusive prefix scan of deg[NN] -> rowptr[NN+1]. Single block, 1024 thr.
__global__ __launch_bounds__(1024) void k_scan(const int* deg, int* rowptr) {
  __shared__ int s[1024];
  __shared__ int carry;
  if (threadIdx.x == 0) carry = 0;
  __syncthreads();
  for (int base = 0; base < NN; base += 1024) {
    int i = base + threadIdx.x;
    int v = (i < NN) ? deg[i] : 0;
    s[threadIdx.x] = v;
    __syncthreads();
    for (int off = 1; off < 1024; off <<= 1) {
      int t = (threadIdx.x >= off) ? s[threadIdx.x - off] : 0;
      __syncthreads();
      s[threadIdx.x] += t;
      __syncthreads();
    }
    if (i < NN) rowptr[i] = carry + s[threadIdx.x] - v;  // exclusive
    __syncthreads();
    if (threadIdx.x == 1023) carry += s[1023];
    __syncthreads();
  }
  if (threadIdx.x == 0) rowptr[NN] = carry;  // == NE
}

__global__ __launch_bounds__(256) void k_copy_fill(const int* rowptr, int* fill) {
  int i = blockIdx.x * 256 + threadIdx.x;
  if (i < NN) fill[i] = rowptr[i];
}

__global__ __launch_bounds__(256) void k_fill(const void* ei, const int* flags,
                                              int* fill, int* csr_src) {
  int e = blockIdx.x * 256 + threadIdx.x;
  if (e >= NE) return;
  int is64 = flags[0];
  int s = lde(ei, e, is64);
  int d = lde(ei, (size_t)NE + e, is64);
  int pos = atomicAdd(&fill[d], 1);
  csr_src[pos] = s;
}

// MFMA GEMM: out[N,128] = in[N,128] @ W[128,128], bf16 inputs, f32 accum.
// Block: 256 thr = 4 waves; wave owns 32 rows (2 M-tiles of 16); full N=128.
// W in LDS, fragment-contiguous: sW[c][n][j] = W[8c+j][n], c in [0,16).
// B-frag(col-tile nt, k-chunk c) for lane = sW[c][nt*16 + (lane&15)][0..8).
// A-frag: lane reads in[row][32q + quad*8 .. +8) (A[m=lane&15][k=quad*8+j]).
// C/D: col = lane&15, row = quad*4 + reg (verified m89/m91).
template <bool XMAYBE>
__global__ __launch_bounds__(256) void k_gemm(const void* in_, const void* W,
                                              const int* flags, float* out) {
  __shared__ alignas(16) short sW[16 * 128 * 8];  // 32 KB
  const int isbf = flags[1];
  const int isx = XMAYBE ? isbf : 0;
  const int tid = threadIdx.x;

  // stage + swizzle W (once)
  for (int idx = tid; idx < DD * DD; idx += 256) {
    int k = idx >> 7, n = idx & 127;
    sW[(k >> 3) * 1024 + n * 8 + (k & 7)] = f2bs(ldf(W, idx, isbf));
  }
  __syncthreads();

  const int wave = tid >> 6;
  const int lane = tid & 63;
  const int quad = lane >> 4;
  const int m16 = lane & 15;
  const int r0 = blockIdx.x * 128 + wave * 32;

  f32x4 acc[2][8];
#pragma unroll
  for (int t = 0; t < 2; t++)
#pragma unroll
    for (int n = 0; n < 8; n++) acc[t][n] = (f32x4){0.f, 0.f, 0.f, 0.f};

#pragma unroll
  for (int q = 0; q < 4; q++) {
    const int kq = q * 32 + quad * 8;
    short8 af[2];
    if (isx) {
      const short* xb = (const short*)in_;
#pragma unroll
      for (int t = 0; t < 2; t++) {
        int row = r0 + t * 16 + m16;
        row = row < NN ? row : NN - 1;  // clamp; garbage rows never stored
        af[t] = *(const short8*)(xb + (size_t)row * DD + kq);
      }
    } else {
      const float* xf = (const float*)in_;
#pragma unroll
      for (int t = 0; t < 2; t++) {
        int row = r0 + t * 16 + m16;
        row = row < NN ? row : NN - 1;
        const float* ap = xf + (size_t)row * DD + kq;
        const float4 u0 = *(const float4*)ap;
        const float4 u1 = *(const float4*)(ap + 4);
        short8 f;
        f[0] = f2bs(u0.x); f[1] = f2bs(u0.y); f[2] = f2bs(u0.z); f[3] = f2bs(u0.w);
        f[4] = f2bs(u1.x); f[5] = f2bs(u1.y); f[6] = f2bs(u1.z); f[7] = f2bs(u1.w);
        af[t] = f;
      }
    }
    const int c = q * 4 + quad;
    const short* bp = sW + c * 1024 + m16 * 8;
#pragma unroll
    for (int n = 0; n < 8; n++) {
      const short8 bf = *(const short8*)(bp + n * 128);
      acc[0][n] = __builtin_amdgcn_mfma_f32_16x16x32_bf16(af[0], bf, acc[0][n], 0, 0, 0);
      acc[1][n] = __builtin_amdgcn_mfma_f32_16x16x32_bf16(af[1], bf, acc[1][n], 0, 0, 0);
    }
  }

#pragma unroll
  for (int t = 0; t < 2; t++)
#pragma unroll
    for (int n = 0; n < 8; n++)
#pragma unroll
      for (int r = 0; r < 4; r++) {
        int row = r0 + t * 16 + quad * 4 + r;
        if (row < NN) out[(size_t)row * DD + n * 16 + m16] = acc[t][n][r];
      }
}

// One wave per node d: agg[d] = dinv[d]*(dinv[d]*h[d] + sum_e dinv[s]*h[s]) + b
__global__ __launch_bounds__(256) void k_agg(const float* h, const float* dinv,
                                             const int* rowptr, const int* csr_src,
                                             const void* bias, const int* flags, float* out) {
  int w = (blockIdx.x * 256 + threadIdx.x) >> 6;
  if (w >= NN) return;
  int lane = threadIdx.x & 63;
  const float2* h2 = (const float2*)h;
  float dd_ = dinv[w];
  float2 hv = h2[(size_t)w * 64 + lane];
  float ax = dd_ * hv.x, ay = dd_ * hv.y;
  int e = rowptr[w], e1 = rowptr[w + 1];
  for (; e + 1 < e1; e += 2) {
    int s0 = csr_src[e], s1 = csr_src[e + 1];
    float c0 = dinv[s0], c1 = dinv[s1];
    float2 v0 = h2[(size_t)s0 * 64 + lane];
    float2 v1 = h2[(size_t)s1 * 64 + lane];
    ax += c0 * v0.x + c1 * v1.x;
    ay += c0 * v0.y + c1 * v1.y;
  }
  if (e < e1) {
    int s0 = csr_src[e];
    float c0 = dinv[s0];
    float2 v0 = h2[(size_t)s0 * 64 + lane];
    ax += c0 * v0.x;
    ay += c0 * v0.y;
  }
  int isbf = flags[1];
  float2 o;
  o.x = dd_ * ax + ldf(bias, 2 * lane + 0, isbf);
  o.y = dd_ * ay + ldf(bias, 2 * lane + 1, isbf);
  ((float2*)out)[(size_t)w * 64 + lane] = o;
}

__global__ void k_zero_stats(float* stats) { stats[threadIdx.x] = 0.f; }  // 256 thr

__global__ __launch_bounds__(128) void k_bn_stats(const float* x, float* stats) {
  int j = threadIdx.x;
  float s = 0.f, q = 0.f;
  for (int r = blockIdx.x; r < NN; r += gridDim.x) {
    float v = x[(size_t)r * DD + j];
    s += v;
    q += v * v;
  }
  atomicAdd(&stats[j], s);
  atomicAdd(&stats[DD + j], q);
}

// FINAL && bf16-inputs -> bf16 out; else f32 out.
template <bool FINAL>
__global__ __launch_bounds__(256) void k_bn_apply(const float* x, const float* stats,
                                                  const void* g, const void* be, const void* al,
                                                  const int* flags, void* out) {
  int i4 = blockIdx.x * 256 + threadIdx.x;
  if (i4 >= NN * 32) return;
  int isbf = flags[1];
  int jq = (i4 & 31) * 4;
  const float inv_n = 1.0f / NN;
  float alpha = ldf(al, 0, isbf);
  const float4 xv = ((const float4*)x)[i4];
  float xa[4] = {xv.x, xv.y, xv.z, xv.w};
  float y[4];
#pragma unroll
  for (int u = 0; u < 4; u++) {
    int j = jq + u;
    float mu = stats[j] * inv_n;
    float var = stats[DD + j] * inv_n - mu * mu;
    float sc = rsqrtf(var + BN_EPS) * ldf(g, j, isbf);
    float v = (xa[u] - mu) * sc + ldf(be, j, isbf);
    y[u] = v > 0.f ? v : alpha * v;
  }
  if (FINAL && isbf) {
    bf16* o = (bf16*)out;
#pragma unroll
    for (int u = 0; u < 4; u++) o[(size_t)i4 * 4 + u] = __float2bfloat16(y[u]);
  } else {
    float4 o = {y[0], y[1], y[2], y[3]};
    ((float4*)out)[i4] = o;
  }
}

extern "C" void kernel_launch(void* const* d_in, const int* in_sizes, int n_in,
                              void* d_out, int out_size, void* d_ws, size_t ws_size,
                              hipStream_t stream) {
  const void* x = d_in[0];
  const void* ei = d_in[1];
  const void* W1 = d_in[2];
  const void* b1 = d_in[3];
  const void* g1 = d_in[4];
  const void* be1 = d_in[5];
  const void* a1 = d_in[6];
  const void* W2 = d_in[7];
  const void* b2 = d_in[8];
  const void* g2 = d_in[9];
  const void* be2 = d_in[10];
  const void* a2 = d_in[11];

  char* w = (char*)d_ws;
  float* dinv = (float*)w;                       // 200000
  int* flags = (int*)(w + 200704);               // 8
  float* stats = (float*)(w + 201728);           // 1024
  int* deg = (int*)(w + 204800);                 // 200000
  int* rowptr = (int*)(w + 404800);              // 200004
  int* fill = (int*)(w + 604816);                // 200000
  int* csr_src = (int*)(w + 1048576);            // 3200000
  float* bufA = (float*)(w + 4456448);           // 25600000
  float* bufB = (float*)(w + 30056448);          // 25600000

  const int NB_N = (NN + 255) / 256;   // 196
  const int NB_E = (NE + 255) / 256;   // 3125
  const int NB_G = (NN + 127) / 128;   // 391 mfma-gemm blocks
  const int NB_V = NN * 32 / 256;      // 6250 (exact)
  const int NB_W = NN * 64 / 256;      // 12500 (exact) one wave per node

  k_detect<<<dim3(1), dim3(64), 0, stream>>>((const int*)ei, (const unsigned short*)x, flags);

  // CSR build (shared by both layers) + dinv
  k_zero_deg<<<dim3(NB_N), dim3(256), 0, stream>>>(deg);
  k_count_deg<<<dim3(NB_E), dim3(256), 0, stream>>>(ei, flags, deg);
  k_dinv<<<dim3(NB_N), dim3(256), 0, stream>>>(deg, dinv);
  k_scan<<<dim3(1), dim3(1024), 0, stream>>>(deg, rowptr);
  k_copy_fill<<<dim3(NB_N), dim3(256), 0, stream>>>(rowptr, fill);
  k_fill<<<dim3(NB_E), dim3(256), 0, stream>>>(ei, flags, fill, csr_src);

  // ---- layer 1 ----
  k_gemm<true><<<dim3(NB_G), dim3(256), 0, stream>>>(x, W1, flags, bufA);
  k_agg<<<dim3(NB_W), dim3(256), 0, stream>>>(bufA, dinv, rowptr, csr_src, b1, flags, bufB);
  k_zero_stats<<<dim3(1), dim3(256), 0, stream>>>(stats);
  k_bn_stats<<<dim3(256), dim3(128), 0, stream>>>(bufB, stats);
  k_bn_apply<false><<<dim3(NB_V), dim3(256), 0, stream>>>(bufB, stats, g1, be1, a1, flags, bufA);

  // ---- layer 2 ----
  k_gemm<false><<<dim3(NB_G), dim3(256), 0, stream>>>(bufA, W2, flags, bufB);
  k_agg<<<dim3(NB_W), dim3(256), 0, stream>>>(bufB, dinv, rowptr, csr_src, b2, flags, bufA);
  k_zero_stats<<<dim3(1), dim3(256), 0, stream>>>(stats);
  k_bn_stats<<<dim3(256), dim3(128), 0, stream>>>(bufA, stats);
  k_bn_apply<true><<<dim3(NB_V), dim3(256), 0, stream>>>(bufA, stats, g2, be2, a2, flags, d_out);
}

// Round 6
// 512.743 us; speedup vs baseline: 6.6465x; 1.2558x over previous
//
#include <hip/hip_runtime.h>
#include <hip/hip_bf16.h>

// 2-layer GCN encoder: (GCNConv -> BatchNorm1d(train) -> PReLU) x 2
// N=50000, E=800000, D=128. Inputs f32 (probed), edge_index int64 (probed),
// output f32. Internal: GEMM in/out bf16 (MFMA), aggregation/BN math f32.
//
// R6: (1) single-block k_scan (90us, 0.17% occ) -> 3-kernel multi-block scan;
//     (2) GEMM writes h as bf16 -> k_agg gathers 256B rows instead of 512B;
//     (3) layer-1 BN/PReLU emits bf16 directly for layer-2 GEMM.
//
// ws layout (bytes):
//   [0       .. +200000)   dinv f32[NN]
//   [200704  .. +8)        flags: [0]=int64?, [1]=bf16-floats?
//   [201728  .. +1024)     BN stats (sum[128], sumsq[128])
//   [204800  .. +200000)   deg   int[NN]
//   [404800  .. +200004)   rowptr int[NN+1]
//   [604816  .. +200000)   fill  int[NN]
//   [804816  .. +784)      partial int[196]
//   [1048576 .. +3.2MB)    csr_src int[NE]
//   [4456448 .. +12.8MB)   hbuf  bf16[NN*DD]  (GEMM out, agg gather src)
//   [17256448.. +12.8MB)   xbuf  bf16[NN*DD]  (layer-1 BN out, GEMM-2 in)
//   [30056448.. +25.6MB)   aggbuf f32[NN*DD]  (agg out, BN in)
// total ~55.7 MB (same footprint as R5)

typedef __hip_bfloat16 bf16;
typedef __attribute__((ext_vector_type(8))) short short8;   // 8 bf16 = 4 VGPR
typedef __attribute__((ext_vector_type(4))) float f32x4;    // MFMA accumulator

#define NN 50000
#define NE 800000
#define DD 128
#define BN_EPS 1e-5f
#define NB196 196

__device__ __forceinline__ float b2f(bf16 v) { return __bfloat162float(v); }
__device__ __forceinline__ float ldf(const void* p, size_t idx, int isbf) {
  return isbf ? b2f(((const bf16*)p)[idx]) : ((const float*)p)[idx];
}
__device__ __forceinline__ int lde(const void* ei, size_t idx, int is64) {
  return is64 ? (int)((const long long*)ei)[idx] : ((const int*)ei)[idx];
}
__device__ __forceinline__ unsigned short f2bs(float v) {
  bf16 b = __float2bfloat16(v);
  return *reinterpret_cast<unsigned short*>(&b);
}
__device__ __forceinline__ float bslo(unsigned int u) {  // low bf16 of packed pair
  return __uint_as_float(u << 16);
}
__device__ __forceinline__ float bshi(unsigned int u) {  // high bf16
  return __uint_as_float(u & 0xFFFF0000u);
}

// 64 threads. flags[0]: int64 edge_index?  flags[1]: bf16 floats?
__global__ void k_detect(const int* ei, const unsigned short* x16, int* flags) {
  int t = threadIdx.x;
  unsigned long long m1 = __ballot(ei[2 * t + 1] != 0);
  int ex = (x16[2 * t] >> 7) & 0xFF;
  unsigned long long m2 = __ballot(ex >= 90 && ex <= 140);
  if (t == 0) {
    flags[0] = (m1 == 0ull) ? 1 : 0;
    flags[1] = (__popcll(m2) >= 48) ? 1 : 0;
  }
}

__global__ __launch_bounds__(256) void k_zero_deg(int* deg) {
  int i = blockIdx.x * 256 + threadIdx.x;
  if (i < NN) deg[i] = 0;
}

__global__ __launch_bounds__(256) void k_count_deg(const void* ei, const int* flags, int* deg) {
  int e = blockIdx.x * 256 + threadIdx.x;
  if (e >= NE) return;
  int d = lde(ei, (size_t)NE + e, flags[0]);
  atomicAdd(&deg[d], 1);
}

__global__ __launch_bounds__(256) void k_dinv(const int* deg, float* dinv) {
  int i = blockIdx.x * 256 + threadIdx.x;
  if (i < NN) dinv[i] = rsqrtf((float)(deg[i] + 1));  // +1 self-loop
}

// Multi-block exclusive scan of deg -> rowptr (3 stages).
__global__ __launch_bounds__(256) void k_scan1(const int* deg, int* rowptr, int* partial) {
  __shared__ int s[256];
  int i = blockIdx.x * 256 + threadIdx.x;
  int v = (i < NN) ? deg[i] : 0;
  s[threadIdx.x] = v;
  __syncthreads();
  for (int off = 1; off < 256; off <<= 1) {
    int t = (threadIdx.x >= off) ? s[threadIdx.x - off] : 0;
    __syncthreads();
    s[threadIdx.x] += t;
    __syncthreads();
  }
  if (i < NN) rowptr[i] = s[threadIdx.x] - v;  // block-local exclusive
  if (threadIdx.x == 255) partial[blockIdx.x] = s[255];
}

__global__ __launch_bounds__(256) void k_scan2(int* partial, int* rowptr) {
  __shared__ int s[256];
  int v = (threadIdx.x < NB196) ? partial[threadIdx.x] : 0;
  s[threadIdx.x] = v;
  __syncthreads();
  for (int off = 1; off < 256; off <<= 1) {
    int t = (threadIdx.x >= off) ? s[threadIdx.x - off] : 0;
    __syncthreads();
    s[threadIdx.x] += t;
    __syncthreads();
  }
  if (threadIdx.x < NB196) partial[threadIdx.x] = s[threadIdx.x] - v;  // exclusive
  if (threadIdx.x == 255) rowptr[NN] = s[255];  // == NE
}

__global__ __launch_bounds__(256) void k_scan3(const int* partial, int* rowptr) {
  int i = blockIdx.x * 256 + threadIdx.x;
  if (i < NN) rowptr[i] += partial[blockIdx.x];
}

__global__ __launch_bounds__(256) void k_copy_fill(const int* rowptr, int* fill) {
  int i = blockIdx.x * 256 + threadIdx.x;
  if (i < NN) fill[i] = rowptr[i];
}

__global__ __launch_bounds__(256) void k_fill(const void* ei, const int* flags,
                                              int* fill, int* csr_src) {
  int e = blockIdx.x * 256 + threadIdx.x;
  if (e >= NE) return;
  int is64 = flags[0];
  int s = lde(ei, e, is64);
  int d = lde(ei, (size_t)NE + e, is64);
  int pos = atomicAdd(&fill[d], 1);
  csr_src[pos] = s;
}

// MFMA GEMM: out[N,128] (bf16) = in[N,128] @ W[128,128], f32 accum.
// Block: 256 thr = 4 waves; wave owns 32 rows (2 M-tiles of 16); full N=128.
// W in LDS fragment-contiguous: sW[c][n][j] = W[8c+j][n].
// XMODE: 0 = probe input dtype (layer 1), 1 = input always bf16 (layer 2).
template <int XMODE>
__global__ __launch_bounds__(256) void k_gemm(const void* in_, const void* W,
                                              const int* flags, unsigned short* out) {
  __shared__ alignas(16) short sW[16 * 128 * 8];  // 32 KB
  const int isbf = flags[1];
  const int isx = (XMODE == 1) ? 1 : isbf;
  const int tid = threadIdx.x;

  for (int idx = tid; idx < DD * DD; idx += 256) {
    int k = idx >> 7, n = idx & 127;
    sW[(k >> 3) * 1024 + n * 8 + (k & 7)] = (short)f2bs(ldf(W, idx, isbf));
  }
  __syncthreads();

  const int wave = tid >> 6;
  const int lane = tid & 63;
  const int quad = lane >> 4;
  const int m16 = lane & 15;
  const int r0 = blockIdx.x * 128 + wave * 32;

  f32x4 acc[2][8];
#pragma unroll
  for (int t = 0; t < 2; t++)
#pragma unroll
    for (int n = 0; n < 8; n++) acc[t][n] = (f32x4){0.f, 0.f, 0.f, 0.f};

#pragma unroll
  for (int q = 0; q < 4; q++) {
    const int kq = q * 32 + quad * 8;
    short8 af[2];
    if (isx) {
      const short* xb = (const short*)in_;
#pragma unroll
      for (int t = 0; t < 2; t++) {
        int row = r0 + t * 16 + m16;
        row = row < NN ? row : NN - 1;  // clamp; garbage rows never stored
        af[t] = *(const short8*)(xb + (size_t)row * DD + kq);
      }
    } else {
      const float* xf = (const float*)in_;
#pragma unroll
      for (int t = 0; t < 2; t++) {
        int row = r0 + t * 16 + m16;
        row = row < NN ? row : NN - 1;
        const float* ap = xf + (size_t)row * DD + kq;
        const float4 u0 = *(const float4*)ap;
        const float4 u1 = *(const float4*)(ap + 4);
        short8 f;
        f[0] = (short)f2bs(u0.x); f[1] = (short)f2bs(u0.y);
        f[2] = (short)f2bs(u0.z); f[3] = (short)f2bs(u0.w);
        f[4] = (short)f2bs(u1.x); f[5] = (short)f2bs(u1.y);
        f[6] = (short)f2bs(u1.z); f[7] = (short)f2bs(u1.w);
        af[t] = f;
      }
    }
    const int c = q * 4 + quad;
    const short* bp = sW + c * 1024 + m16 * 8;
#pragma unroll
    for (int n = 0; n < 8; n++) {
      const short8 bfrag = *(const short8*)(bp + n * 128);
      acc[0][n] = __builtin_amdgcn_mfma_f32_16x16x32_bf16(af[0], bfrag, acc[0][n], 0, 0, 0);
      acc[1][n] = __builtin_amdgcn_mfma_f32_16x16x32_bf16(af[1], bfrag, acc[1][n], 0, 0, 0);
    }
  }

#pragma unroll
  for (int t = 0; t < 2; t++)
#pragma unroll
    for (int n = 0; n < 8; n++)
#pragma unroll
      for (int r = 0; r < 4; r++) {
        int row = r0 + t * 16 + quad * 4 + r;
        if (row < NN) out[(size_t)row * DD + n * 16 + m16] = f2bs(acc[t][n][r]);
      }
}

// One wave per node d: agg[d] = dinv[d]*(dinv[d]*h[d] + sum_e dinv[s]*h[s]) + b
// h is bf16; lane owns 2 columns (one packed uint, 256B/row coalesced).
__global__ __launch_bounds__(256) void k_agg(const unsigned short* h, const float* dinv,
                                             const int* rowptr, const int* csr_src,
                                             const void* bias, const int* flags, float* out) {
  int w = (blockIdx.x * 256 + threadIdx.x) >> 6;
  if (w >= NN) return;
  int lane = threadIdx.x & 63;
  const unsigned int* h1 = (const unsigned int*)h;
  float dd_ = dinv[w];
  unsigned int hv = h1[(size_t)w * 64 + lane];
  float ax = dd_ * bslo(hv), ay = dd_ * bshi(hv);
  int e = rowptr[w], e1 = rowptr[w + 1];
  for (; e + 1 < e1; e += 2) {  // 2-edge unroll: two row-loads in flight
    int s0 = csr_src[e], s1 = csr_src[e + 1];
    float c0 = dinv[s0], c1 = dinv[s1];
    unsigned int v0 = h1[(size_t)s0 * 64 + lane];
    unsigned int v1 = h1[(size_t)s1 * 64 + lane];
    ax += c0 * bslo(v0) + c1 * bslo(v1);
    ay += c0 * bshi(v0) + c1 * bshi(v1);
  }
  if (e < e1) {
    int s0 = csr_src[e];
    float c0 = dinv[s0];
    unsigned int v0 = h1[(size_t)s0 * 64 + lane];
    ax += c0 * bslo(v0);
    ay += c0 * bshi(v0);
  }
  int isbf = flags[1];
  float2 o;
  o.x = dd_ * ax + ldf(bias, 2 * lane + 0, isbf);
  o.y = dd_ * ay + ldf(bias, 2 * lane + 1, isbf);
  ((float2*)out)[(size_t)w * 64 + lane] = o;
}

__global__ void k_zero_stats(float* stats) { stats[threadIdx.x] = 0.f; }  // 256 thr

__global__ __launch_bounds__(128) void k_bn_stats(const float* x, float* stats) {
  int j = threadIdx.x;
  float s = 0.f, q = 0.f;
  for (int r = blockIdx.x; r < NN; r += gridDim.x) {
    float v = x[(size_t)r * DD + j];
    s += v;
    q += v * v;
  }
  atomicAdd(&stats[j], s);
  atomicAdd(&stats[DD + j], q);
}

// MID=true: write bf16 (mid-layer, feeds GEMM-2). MID=false: final -> d_out,
// f32 unless inputs were bf16 (then bf16).
template <bool MID>
__global__ __launch_bounds__(256) void k_bn_apply(const float* x, const float* stats,
                                                  const void* g, const void* be, const void* al,
                                                  const int* flags, void* out) {
  int i4 = blockIdx.x * 256 + threadIdx.x;
  if (i4 >= NN * 32) return;
  int isbf = flags[1];
  int jq = (i4 & 31) * 4;
  const float inv_n = 1.0f / NN;
  float alpha = ldf(al, 0, isbf);
  const float4 xv = ((const float4*)x)[i4];
  float xa[4] = {xv.x, xv.y, xv.z, xv.w};
  float y[4];
#pragma unroll
  for (int u = 0; u < 4; u++) {
    int j = jq + u;
    float mu = stats[j] * inv_n;
    float var = stats[DD + j] * inv_n - mu * mu;
    float sc = rsqrtf(var + BN_EPS) * ldf(g, j, isbf);
    float v = (xa[u] - mu) * sc + ldf(be, j, isbf);
    y[u] = v > 0.f ? v : alpha * v;
  }
  if (MID || isbf) {
    uint2 o;
    o.x = ((unsigned int)f2bs(y[1]) << 16) | f2bs(y[0]);
    o.y = ((unsigned int)f2bs(y[3]) << 16) | f2bs(y[2]);
    ((uint2*)out)[i4] = o;
  } else {
    float4 o = {y[0], y[1], y[2], y[3]};
    ((float4*)out)[i4] = o;
  }
}

extern "C" void kernel_launch(void* const* d_in, const int* in_sizes, int n_in,
                              void* d_out, int out_size, void* d_ws, size_t ws_size,
                              hipStream_t stream) {
  const void* x = d_in[0];
  const void* ei = d_in[1];
  const void* W1 = d_in[2];
  const void* b1 = d_in[3];
  const void* g1 = d_in[4];
  const void* be1 = d_in[5];
  const void* a1 = d_in[6];
  const void* W2 = d_in[7];
  const void* b2 = d_in[8];
  const void* g2 = d_in[9];
  const void* be2 = d_in[10];
  const void* a2 = d_in[11];

  char* w = (char*)d_ws;
  float* dinv = (float*)w;                              // 200000
  int* flags = (int*)(w + 200704);                      // 8
  float* stats = (float*)(w + 201728);                  // 1024
  int* deg = (int*)(w + 204800);                        // 200000
  int* rowptr = (int*)(w + 404800);                     // 200004
  int* fill = (int*)(w + 604816);                       // 200000
  int* partial = (int*)(w + 804816);                    // 784
  int* csr_src = (int*)(w + 1048576);                   // 3200000
  unsigned short* hbuf = (unsigned short*)(w + 4456448);   // 12800000
  unsigned short* xbuf = (unsigned short*)(w + 17256448);  // 12800000
  float* aggbuf = (float*)(w + 30056448);                  // 25600000

  const int NB_N = (NN + 255) / 256;   // 196
  const int NB_E = (NE + 255) / 256;   // 3125
  const int NB_G = (NN + 127) / 128;   // 391
  const int NB_V = NN * 32 / 256;      // 6250 (exact)
  const int NB_W = NN * 64 / 256;      // 12500 (exact)

  k_detect<<<dim3(1), dim3(64), 0, stream>>>((const int*)ei, (const unsigned short*)x, flags);

  // CSR build (shared by both layers) + dinv
  k_zero_deg<<<dim3(NB_N), dim3(256), 0, stream>>>(deg);
  k_count_deg<<<dim3(NB_E), dim3(256), 0, stream>>>(ei, flags, deg);
  k_dinv<<<dim3(NB_N), dim3(256), 0, stream>>>(deg, dinv);
  k_scan1<<<dim3(NB_N), dim3(256), 0, stream>>>(deg, rowptr, partial);
  k_scan2<<<dim3(1), dim3(256), 0, stream>>>(partial, rowptr);
  k_scan3<<<dim3(NB_N), dim3(256), 0, stream>>>(partial, rowptr);
  k_copy_fill<<<dim3(NB_N), dim3(256), 0, stream>>>(rowptr, fill);
  k_fill<<<dim3(NB_E), dim3(256), 0, stream>>>(ei, flags, fill, csr_src);

  // ---- layer 1 ----
  k_gemm<0><<<dim3(NB_G), dim3(256), 0, stream>>>(x, W1, flags, hbuf);
  k_agg<<<dim3(NB_W), dim3(256), 0, stream>>>(hbuf, dinv, rowptr, csr_src, b1, flags, aggbuf);
  k_zero_stats<<<dim3(1), dim3(256), 0, stream>>>(stats);
  k_bn_stats<<<dim3(256), dim3(128), 0, stream>>>(aggbuf, stats);
  k_bn_apply<true><<<dim3(NB_V), dim3(256), 0, stream>>>(aggbuf, stats, g1, be1, a1, flags, xbuf);

  // ---- layer 2 ----
  k_gemm<1><<<dim3(NB_G), dim3(256), 0, stream>>>(xbuf, W2, flags, hbuf);
  k_agg<<<dim3(NB_W), dim3(256), 0, stream>>>(hbuf, dinv, rowptr, csr_src, b2, flags, aggbuf);
  k_zero_stats<<<dim3(1), dim3(256), 0, stream>>>(stats);
  k_bn_stats<<<dim3(256), dim3(128), 0, stream>>>(aggbuf, stats);
  k_bn_apply<false><<<dim3(NB_V), dim3(256), 0, stream>>>(aggbuf, stats, g2, be2, a2, flags, d_out);
}

// Round 7
// 437.614 us; speedup vs baseline: 7.7875x; 1.1717x over previous
//
#include <hip/hip_runtime.h>
#include <hip/hip_bf16.h>

// 2-layer GCN encoder: (GCNConv -> BatchNorm1d(train) -> PReLU) x 2
// N=50000, E=800000, D=128. Inputs f32 (probed), edge_index int64 (probed),
// output f32. Internal: GEMM in/out bf16 (MFMA), aggregation/BN math f32.
//
// R7: (1) GEMM epilogue pre-scales rows by dinv -> k_agg loses the per-edge
//     dependent dinv[s] gather; 4-edge unroll for MLP.
//     (2) hbuf stored in MFMA-native packed layout: u32 slot s of a row holds
//     bf16 cols (s, s+64) -> epilogue stores packed dwords (no repack LDS).
//     (3) layer-1 BN+PReLU fused into GEMM-2's A-load (sc/sh in LDS); xbuf
//     and bn_apply<mid> eliminated.
//     (4) bn_stats grid 256 -> 1024 blocks (was 0.25 wave/CU).
//
// ws layout (bytes):
//   [0       .. +200000)   dinv f32[NN]
//   [200704  .. +8)        flags: [0]=int64?, [1]=bf16-floats?
//   [201728  .. +1024)     BN stats (sum[128], sumsq[128])
//   [204800  .. +200000)   deg   int[NN]
//   [404800  .. +200004)   rowptr int[NN+1]
//   [604816  .. +200000)   fill  int[NN]
//   [804816  .. +784)      partial int[196]
//   [1048576 .. +3.2MB)    csr_src int[NE]
//   [4456448 .. +12.8MB)   hbuf  bf16[NN*DD] packed-slot layout (dinv-scaled)
//   [30056448.. +25.6MB)   aggbuf f32[NN*DD] row-major
// total ~55.7 MB

typedef __hip_bfloat16 bf16;
typedef __attribute__((ext_vector_type(8))) short short8;   // 8 bf16 = 4 VGPR
typedef __attribute__((ext_vector_type(4))) float f32x4;    // MFMA accumulator

#define NN 50000
#define NE 800000
#define DD 128
#define BN_EPS 1e-5f
#define NB196 196

__device__ __forceinline__ float b2f(bf16 v) { return __bfloat162float(v); }
__device__ __forceinline__ float ldf(const void* p, size_t idx, int isbf) {
  return isbf ? b2f(((const bf16*)p)[idx]) : ((const float*)p)[idx];
}
__device__ __forceinline__ int lde(const void* ei, size_t idx, int is64) {
  return is64 ? (int)((const long long*)ei)[idx] : ((const int*)ei)[idx];
}
__device__ __forceinline__ unsigned int f2bs(float v) {
  bf16 b = __float2bfloat16(v);
  return (unsigned int)*reinterpret_cast<unsigned short*>(&b);
}
__device__ __forceinline__ float bslo(unsigned int u) { return __uint_as_float(u << 16); }
__device__ __forceinline__ float bshi(unsigned int u) { return __uint_as_float(u & 0xFFFF0000u); }

// 64 threads. flags[0]: int64 edge_index?  flags[1]: bf16 floats?
__global__ void k_detect(const int* ei, const unsigned short* x16, int* flags) {
  int t = threadIdx.x;
  unsigned long long m1 = __ballot(ei[2 * t + 1] != 0);
  int ex = (x16[2 * t] >> 7) & 0xFF;
  unsigned long long m2 = __ballot(ex >= 90 && ex <= 140);
  if (t == 0) {
    flags[0] = (m1 == 0ull) ? 1 : 0;
    flags[1] = (__popcll(m2) >= 48) ? 1 : 0;
  }
}

__global__ __launch_bounds__(256) void k_zero_deg(int* deg) {
  int i = blockIdx.x * 256 + threadIdx.x;
  if (i < NN) deg[i] = 0;
}

__global__ __launch_bounds__(256) void k_count_deg(const void* ei, const int* flags, int* deg) {
  int e = blockIdx.x * 256 + threadIdx.x;
  if (e >= NE) return;
  int d = lde(ei, (size_t)NE + e, flags[0]);
  atomicAdd(&deg[d], 1);
}

__global__ __launch_bounds__(256) void k_dinv(const int* deg, float* dinv) {
  int i = blockIdx.x * 256 + threadIdx.x;
  if (i < NN) dinv[i] = rsqrtf((float)(deg[i] + 1));  // +1 self-loop
}

// Multi-block exclusive scan of deg -> rowptr (3 stages).
__global__ __launch_bounds__(256) void k_scan1(const int* deg, int* rowptr, int* partial) {
  __shared__ int s[256];
  int i = blockIdx.x * 256 + threadIdx.x;
  int v = (i < NN) ? deg[i] : 0;
  s[threadIdx.x] = v;
  __syncthreads();
  for (int off = 1; off < 256; off <<= 1) {
    int t = (threadIdx.x >= off) ? s[threadIdx.x - off] : 0;
    __syncthreads();
    s[threadIdx.x] += t;
    __syncthreads();
  }
  if (i < NN) rowptr[i] = s[threadIdx.x] - v;  // block-local exclusive
  if (threadIdx.x == 255) partial[blockIdx.x] = s[255];
}

__global__ __launch_bounds__(256) void k_scan2(int* partial, int* rowptr) {
  __shared__ int s[256];
  int v = (threadIdx.x < NB196) ? partial[threadIdx.x] : 0;
  s[threadIdx.x] = v;
  __syncthreads();
  for (int off = 1; off < 256; off <<= 1) {
    int t = (threadIdx.x >= off) ? s[threadIdx.x - off] : 0;
    __syncthreads();
    s[threadIdx.x] += t;
    __syncthreads();
  }
  if (threadIdx.x < NB196) partial[threadIdx.x] = s[threadIdx.x] - v;  // exclusive
  if (threadIdx.x == 255) rowptr[NN] = s[255];  // == NE
}

__global__ __launch_bounds__(256) void k_scan3(const int* partial, int* rowptr) {
  int i = blockIdx.x * 256 + threadIdx.x;
  if (i < NN) rowptr[i] += partial[blockIdx.x];
}

__global__ __launch_bounds__(256) void k_copy_fill(const int* rowptr, int* fill) {
  int i = blockIdx.x * 256 + threadIdx.x;
  if (i < NN) fill[i] = rowptr[i];
}

__global__ __launch_bounds__(256) void k_fill(const void* ei, const int* flags,
                                              int* fill, int* csr_src) {
  int e = blockIdx.x * 256 + threadIdx.x;
  if (e >= NE) return;
  int is64 = flags[0];
  int s = lde(ei, e, is64);
  int d = lde(ei, (size_t)NE + e, is64);
  int pos = atomicAdd(&fill[d], 1);
  csr_src[pos] = s;
}

// MFMA GEMM. out = dinv-prescaled bf16 in packed-slot layout:
// row r, u32 slot s in [0,64) holds bf16 pair (col s, col s+64).
// Block: 256 thr = 4 waves; wave owns 32 rows (2 M-tiles of 16); full N=128.
// W in LDS fragment-contiguous: sW[c][n][j] = W[8c+j][n].
// XMODE 0: layer-1 input (probe f32/bf16, row-major).
// XMODE 2: layer-2 input = aggbuf f32 row-major, with fused BN+PReLU from
//          stats/g/be/al (per-col sc/sh staged in LDS).
template <int XMODE>
__global__ __launch_bounds__(256) void k_gemm(const void* in_, const void* W,
                                              const int* flags, const float* dinv,
                                              const float* stats, const void* g,
                                              const void* be, const void* al,
                                              unsigned int* out) {
  __shared__ alignas(16) short sW[16 * 128 * 8];  // 32 KB
  __shared__ float sSc[DD], sSh[DD], sAl;
  const int isbf = flags[1];
  const int tid = threadIdx.x;

  for (int idx = tid; idx < DD * DD; idx += 256) {
    int k = idx >> 7, n = idx & 127;
    sW[(k >> 3) * 1024 + n * 8 + (k & 7)] = (short)f2bs(ldf(W, idx, isbf));
  }
  if (XMODE == 2) {
    if (tid < DD) {
      const float inv_n = 1.0f / NN;
      float mu = stats[tid] * inv_n;
      float var = stats[DD + tid] * inv_n - mu * mu;
      float sc = rsqrtf(var + BN_EPS) * ldf(g, tid, isbf);
      sSc[tid] = sc;
      sSh[tid] = ldf(be, tid, isbf) - mu * sc;
    }
    if (tid == 0) sAl = ldf(al, 0, isbf);
  }
  __syncthreads();

  const int wave = tid >> 6;
  const int lane = tid & 63;
  const int quad = lane >> 4;
  const int m16 = lane & 15;
  const int r0 = blockIdx.x * 128 + wave * 32;

  f32x4 acc[2][8];
#pragma unroll
  for (int t = 0; t < 2; t++)
#pragma unroll
    for (int n = 0; n < 8; n++) acc[t][n] = (f32x4){0.f, 0.f, 0.f, 0.f};

#pragma unroll
  for (int q = 0; q < 4; q++) {
    const int kq = q * 32 + quad * 8;
    short8 af[2];
#pragma unroll
    for (int t = 0; t < 2; t++) {
      int row = r0 + t * 16 + m16;
      row = row < NN ? row : NN - 1;  // clamp; garbage rows never stored
      if (XMODE == 0 && isbf) {
        af[t] = *(const short8*)((const short*)in_ + (size_t)row * DD + kq);
      } else {
        const float* ap = (const float*)in_ + (size_t)row * DD + kq;
        const float4 u0 = *(const float4*)ap;
        const float4 u1 = *(const float4*)(ap + 4);
        float v[8] = {u0.x, u0.y, u0.z, u0.w, u1.x, u1.y, u1.z, u1.w};
        short8 f;
#pragma unroll
        for (int jj = 0; jj < 8; jj++) {
          float y = v[jj];
          if (XMODE == 2) {
            y = y * sSc[kq + jj] + sSh[kq + jj];
            y = y > 0.f ? y : sAl * y;
          }
          f[jj] = (short)f2bs(y);
        }
        af[t] = f;
      }
    }
    const int c = q * 4 + quad;
    const short* bp = sW + c * 1024 + m16 * 8;
#pragma unroll
    for (int n = 0; n < 8; n++) {
      const short8 bfrag = *(const short8*)(bp + n * 128);
      acc[0][n] = __builtin_amdgcn_mfma_f32_16x16x32_bf16(af[0], bfrag, acc[0][n], 0, 0, 0);
      acc[1][n] = __builtin_amdgcn_mfma_f32_16x16x32_bf16(af[1], bfrag, acc[1][n], 0, 0, 0);
    }
  }

  // epilogue: prescale by dinv[row], pack (col, col+64) into one u32 slot
#pragma unroll
  for (int t = 0; t < 2; t++)
#pragma unroll
    for (int r = 0; r < 4; r++) {
      int row = r0 + t * 16 + quad * 4 + r;
      if (row < NN) {
        float di = dinv[row];
        unsigned int* orow = out + (size_t)row * 64;
#pragma unroll
        for (int n = 0; n < 4; n++) {
          unsigned int p = (f2bs(di * acc[t][n + 4][r]) << 16) | f2bs(di * acc[t][n][r]);
          orow[n * 16 + m16] = p;
        }
      }
    }
}

// One wave per node d. hs = dinv-prescaled rows in packed-slot layout:
// slot lane = cols (lane, lane+64).
// agg[d] = dinv[d]*(hs[d] + sum_e hs[s]) + b, written row-major f32.
__global__ __launch_bounds__(256) void k_agg(const unsigned int* hs, const float* dinv,
                                             const int* rowptr, const int* csr_src,
                                             const void* bias, const int* flags, float* out) {
  int w = (blockIdx.x * 256 + threadIdx.x) >> 6;
  if (w >= NN) return;
  int lane = threadIdx.x & 63;
  float dd_ = dinv[w];
  unsigned int hv = hs[(size_t)w * 64 + lane];
  float ax = bslo(hv), ay = bshi(hv);
  int e = rowptr[w], e1 = rowptr[w + 1];
  for (; e + 3 < e1; e += 4) {  // 4 row-loads in flight
    int s0 = csr_src[e], s1 = csr_src[e + 1], s2 = csr_src[e + 2], s3 = csr_src[e + 3];
    unsigned int v0 = hs[(size_t)s0 * 64 + lane];
    unsigned int v1 = hs[(size_t)s1 * 64 + lane];
    unsigned int v2 = hs[(size_t)s2 * 64 + lane];
    unsigned int v3 = hs[(size_t)s3 * 64 + lane];
    ax += bslo(v0) + bslo(v1) + bslo(v2) + bslo(v3);
    ay += bshi(v0) + bshi(v1) + bshi(v2) + bshi(v3);
  }
  for (; e < e1; e++) {
    unsigned int v0 = hs[(size_t)csr_src[e] * 64 + lane];
    ax += bslo(v0);
    ay += bshi(v0);
  }
  int isbf = flags[1];
  float* orow = out + (size_t)w * DD;
  orow[lane] = dd_ * ax + ldf(bias, lane, isbf);
  orow[lane + 64] = dd_ * ay + ldf(bias, lane + 64, isbf);
}

__global__ void k_zero_stats(float* stats) { stats[threadIdx.x] = 0.f; }  // 256 thr

__global__ __launch_bounds__(128) void k_bn_stats(const float* x, float* stats) {
  int j = threadIdx.x;
  float s = 0.f, q = 0.f;
  for (int r = blockIdx.x; r < NN; r += gridDim.x) {
    float v = x[(size_t)r * DD + j];
    s += v;
    q += v * v;
  }
  atomicAdd(&stats[j], s);
  atomicAdd(&stats[DD + j], q);
}

// Final BN+PReLU -> d_out (f32 unless inputs were bf16).
__global__ __launch_bounds__(256) void k_bn_apply(const float* x, const float* stats,
                                                  const void* g, const void* be, const void* al,
                                                  const int* flags, void* out) {
  int i4 = blockIdx.x * 256 + threadIdx.x;
  if (i4 >= NN * 32) return;
  int isbf = flags[1];
  int jq = (i4 & 31) * 4;
  const float inv_n = 1.0f / NN;
  float alpha = ldf(al, 0, isbf);
  const float4 xv = ((const float4*)x)[i4];
  float xa[4] = {xv.x, xv.y, xv.z, xv.w};
  float y[4];
#pragma unroll
  for (int u = 0; u < 4; u++) {
    int j = jq + u;
    float mu = stats[j] * inv_n;
    float var = stats[DD + j] * inv_n - mu * mu;
    float sc = rsqrtf(var + BN_EPS) * ldf(g, j, isbf);
    float v = (xa[u] - mu) * sc + ldf(be, j, isbf);
    y[u] = v > 0.f ? v : alpha * v;
  }
  if (isbf) {
    uint2 o;
    o.x = (f2bs(y[1]) << 16) | f2bs(y[0]);
    o.y = (f2bs(y[3]) << 16) | f2bs(y[2]);
    ((uint2*)out)[i4] = o;
  } else {
    float4 o = {y[0], y[1], y[2], y[3]};
    ((float4*)out)[i4] = o;
  }
}

extern "C" void kernel_launch(void* const* d_in, const int* in_sizes, int n_in,
                              void* d_out, int out_size, void* d_ws, size_t ws_size,
                              hipStream_t stream) {
  const void* x = d_in[0];
  const void* ei = d_in[1];
  const void* W1 = d_in[2];
  const void* b1 = d_in[3];
  const void* g1 = d_in[4];
  const void* be1 = d_in[5];
  const void* a1 = d_in[6];
  const void* W2 = d_in[7];
  const void* b2 = d_in[8];
  const void* g2 = d_in[9];
  const void* be2 = d_in[10];
  const void* a2 = d_in[11];

  char* w = (char*)d_ws;
  float* dinv = (float*)w;                              // 200000
  int* flags = (int*)(w + 200704);                      // 8
  float* stats = (float*)(w + 201728);                  // 1024
  int* deg = (int*)(w + 204800);                        // 200000
  int* rowptr = (int*)(w + 404800);                     // 200004
  int* fill = (int*)(w + 604816);                       // 200000
  int* partial = (int*)(w + 804816);                    // 784
  int* csr_src = (int*)(w + 1048576);                   // 3200000
  unsigned int* hbuf = (unsigned int*)(w + 4456448);    // 12800000 (packed slots)
  float* aggbuf = (float*)(w + 30056448);               // 25600000

  const int NB_N = (NN + 255) / 256;   // 196
  const int NB_E = (NE + 255) / 256;   // 3125
  const int NB_G = (NN + 127) / 128;   // 391
  const int NB_V = NN * 32 / 256;      // 6250 (exact)
  const int NB_W = NN * 64 / 256;      // 12500 (exact)

  k_detect<<<dim3(1), dim3(64), 0, stream>>>((const int*)ei, (const unsigned short*)x, flags);

  // CSR build (shared by both layers) + dinv
  k_zero_deg<<<dim3(NB_N), dim3(256), 0, stream>>>(deg);
  k_count_deg<<<dim3(NB_E), dim3(256), 0, stream>>>(ei, flags, deg);
  k_dinv<<<dim3(NB_N), dim3(256), 0, stream>>>(deg, dinv);
  k_scan1<<<dim3(NB_N), dim3(256), 0, stream>>>(deg, rowptr, partial);
  k_scan2<<<dim3(1), dim3(256), 0, stream>>>(partial, rowptr);
  k_scan3<<<dim3(NB_N), dim3(256), 0, stream>>>(partial, rowptr);
  k_copy_fill<<<dim3(NB_N), dim3(256), 0, stream>>>(rowptr, fill);
  k_fill<<<dim3(NB_E), dim3(256), 0, stream>>>(ei, flags, fill, csr_src);

  k_zero_stats<<<dim3(1), dim3(256), 0, stream>>>(stats);

  // ---- layer 1 ----
  k_gemm<0><<<dim3(NB_G), dim3(256), 0, stream>>>(x, W1, flags, dinv,
                                                  nullptr, nullptr, nullptr, nullptr, hbuf);
  k_agg<<<dim3(NB_W), dim3(256), 0, stream>>>(hbuf, dinv, rowptr, csr_src, b1, flags, aggbuf);
  k_bn_stats<<<dim3(1024), dim3(128), 0, stream>>>(aggbuf, stats);

  // ---- layer 2 (BN1+PReLU fused into GEMM A-path) ----
  k_gemm<2><<<dim3(NB_G), dim3(256), 0, stream>>>(aggbuf, W2, flags, dinv,
                                                  stats, g1, be1, a1, hbuf);
  k_agg<<<dim3(NB_W), dim3(256), 0, stream>>>(hbuf, dinv, rowptr, csr_src, b2, flags, aggbuf);
  k_zero_stats<<<dim3(1), dim3(256), 0, stream>>>(stats);
  k_bn_stats<<<dim3(1024), dim3(128), 0, stream>>>(aggbuf, stats);
  k_bn_apply<<<dim3(NB_V), dim3(256), 0, stream>>>(aggbuf, stats, g2, be2, a2, flags, d_out);
}

// Round 8
// 379.222 us; speedup vs baseline: 8.9866x; 1.1540x over previous
//
#include <hip/hip_runtime.h>
#include <hip/hip_bf16.h>

// 2-layer GCN encoder: (GCNConv -> BatchNorm1d(train) -> PReLU) x 2
// N=50000, E=800000, D=128. Inputs f32 (probed), edge_index int64 (probed),
// output f32. Internal: GEMM/agg buffers bf16, math f32.
//
// R8: (1) k_fill (57us, 52.7MB HBM writes from 800k random 4B stores) ->
//     two-phase binned CSR build: k_bin (49 dst-buckets of 1024 nodes,
//     per-block reserved segments -> L2-coalesced writes) + k_fill2 (exact
//     fill inside ~65KB L2-resident windows).
//     (2) aggbuf f32 -> bf16 row-major (halves agg writes, bn_stats reads,
//     gemm2 A-reads, bn_apply reads).
//     (3) k_prep pre-swizzles W1/W2 to bf16 fragment layout once; gemm LDS
//     staging is a raw 16B copy (no cvt).
//     (4) launch folds: dinv->scan1, fill/tail init->scan3, stats zero->
//     prep (L1) and k_agg (L2).
//
// ws layout (bytes):
//   [0       .. +200000)   dinv f32[NN]
//   [200704  .. +8)        flags: [0]=int64?, [1]=bf16-floats?
//   [201728  .. +1024)     BN stats (sum[128], sumsq[128])
//   [204800  .. +200000)   deg   int[NN]
//   [404800  .. +200004)   rowptr int[NN+1]
//   [604816  .. +200000)   fill  int[NN]
//   [804816  .. +784)      partial int[196]
//   [805632  .. +256)      tail int[64]
//   [1048576 .. +3.2MB)    csr_src int[NE]
//   [4456448 .. +12.8MB)   hbuf  bf16[NN*DD] packed-slot layout (dinv-scaled)
//   [17256448.. +32768)    wp1 bf16[128*128] swizzled
//   [17289216.. +32768)    wp2 bf16[128*128] swizzled
//   [30056448.. +12.8MB)   aggbuf bf16[NN*DD] row-major
//   [42856448.. +6.4MB)    binned uint2[NE]
// total ~49.3 MB

typedef __hip_bfloat16 bf16;
typedef __attribute__((ext_vector_type(8))) short short8;   // 8 bf16 = 4 VGPR
typedef __attribute__((ext_vector_type(4))) float f32x4;    // MFMA accumulator

#define NN 50000
#define NE 800000
#define DD 128
#define BN_EPS 1e-5f
#define NB196 196
#define BIN_CHUNK 3125   // NE / 256 exactly

__device__ __forceinline__ float b2f(bf16 v) { return __bfloat162float(v); }
__device__ __forceinline__ float ldf(const void* p, size_t idx, int isbf) {
  return isbf ? b2f(((const bf16*)p)[idx]) : ((const float*)p)[idx];
}
__device__ __forceinline__ int lde(const void* ei, size_t idx, int is64) {
  return is64 ? (int)((const long long*)ei)[idx] : ((const int*)ei)[idx];
}
__device__ __forceinline__ unsigned int f2bs(float v) {
  bf16 b = __float2bfloat16(v);
  return (unsigned int)*reinterpret_cast<unsigned short*>(&b);
}
__device__ __forceinline__ float bslo(unsigned int u) { return __uint_as_float(u << 16); }
__device__ __forceinline__ float bshi(unsigned int u) { return __uint_as_float(u & 0xFFFF0000u); }
__device__ __forceinline__ float s2f(short v) {
  return __uint_as_float(((unsigned int)(unsigned short)v) << 16);
}

// 64 threads. flags[0]: int64 edge_index?  flags[1]: bf16 floats?
__global__ void k_detect(const int* ei, const unsigned short* x16, int* flags) {
  int t = threadIdx.x;
  unsigned long long m1 = __ballot(ei[2 * t + 1] != 0);
  int ex = (x16[2 * t] >> 7) & 0xFF;
  unsigned long long m2 = __ballot(ex >= 90 && ex <= 140);
  if (t == 0) {
    flags[0] = (m1 == 0ull) ? 1 : 0;
    flags[1] = (__popcll(m2) >= 48) ? 1 : 0;
  }
}

// Pre-swizzle W1/W2 into bf16 fragment layout: wp[(k>>3)*1024 + n*8 + (k&7)].
// Blocks 0..63 -> W1, 64..127 -> W2. Block 127 also zeroes BN stats.
__global__ __launch_bounds__(256) void k_prep(const void* W1, const void* W2,
                                              const int* flags,
                                              unsigned short* wp1, unsigned short* wp2,
                                              float* stats) {
  const int isbf = flags[1];
  const void* W = blockIdx.x < 64 ? W1 : W2;
  unsigned short* wp = blockIdx.x < 64 ? wp1 : wp2;
  int idx = (blockIdx.x & 63) * 256 + threadIdx.x;
  int k = idx >> 7, n = idx & 127;
  wp[(k >> 3) * 1024 + n * 8 + (k & 7)] = (unsigned short)f2bs(ldf(W, idx, isbf));
  if (blockIdx.x == 127) stats[threadIdx.x] = 0.f;
}

__global__ __launch_bounds__(256) void k_zero_deg(int* deg) {
  int i = blockIdx.x * 256 + threadIdx.x;
  if (i < NN) deg[i] = 0;
}

__global__ __launch_bounds__(256) void k_count_deg(const void* ei, const int* flags, int* deg) {
  int e = blockIdx.x * 256 + threadIdx.x;
  if (e >= NE) return;
  int d = lde(ei, (size_t)NE + e, flags[0]);
  atomicAdd(&deg[d], 1);
}

// Multi-block exclusive scan of deg -> rowptr (3 stages). Stage 1 also dinv.
__global__ __launch_bounds__(256) void k_scan1(const int* deg, int* rowptr, int* partial,
                                               float* dinv) {
  __shared__ int s[256];
  int i = blockIdx.x * 256 + threadIdx.x;
  int v = (i < NN) ? deg[i] : 0;
  if (i < NN) dinv[i] = rsqrtf((float)(v + 1));  // +1 self-loop
  s[threadIdx.x] = v;
  __syncthreads();
  for (int off = 1; off < 256; off <<= 1) {
    int t = (threadIdx.x >= off) ? s[threadIdx.x - off] : 0;
    __syncthreads();
    s[threadIdx.x] += t;
    __syncthreads();
  }
  if (i < NN) rowptr[i] = s[threadIdx.x] - v;  // block-local exclusive
  if (threadIdx.x == 255) partial[blockIdx.x] = s[255];
}

__global__ __launch_bounds__(256) void k_scan2(int* partial, int* rowptr) {
  __shared__ int s[256];
  int v = (threadIdx.x < NB196) ? partial[threadIdx.x] : 0;
  s[threadIdx.x] = v;
  __syncthreads();
  for (int off = 1; off < 256; off <<= 1) {
    int t = (threadIdx.x >= off) ? s[threadIdx.x - off] : 0;
    __syncthreads();
    s[threadIdx.x] += t;
    __syncthreads();
  }
  if (threadIdx.x < NB196) partial[threadIdx.x] = s[threadIdx.x] - v;  // exclusive
  if (threadIdx.x == 255) rowptr[NN] = s[255];  // == NE
}

// Stage 3: add block offsets; init fill[] and bucket tails.
__global__ __launch_bounds__(256) void k_scan3(const int* partial, int* rowptr,
                                               int* fill, int* tail) {
  int i = blockIdx.x * 256 + threadIdx.x;
  if (i < NN) {
    int v = rowptr[i] + partial[blockIdx.x];
    rowptr[i] = v;
    fill[i] = v;
    if ((i & 1023) == 0) tail[i >> 10] = v;  // bucket base = rowptr[b<<10]
  }
}

// Phase A: bin edges by dst-bucket (d>>10, 49 buckets) into binned[] (s,d).
// 256 blocks x 3125 edges. Per-block reserved segments -> L2-coalesced writes.
__global__ __launch_bounds__(256) void k_bin(const void* ei, const int* flags,
                                             int* tail, uint2* binned) {
  __shared__ int cnt[64], cur[64], gb[64];
  const int is64 = flags[0];
  const int tid = threadIdx.x;
  const int e0 = blockIdx.x * BIN_CHUNK;
  if (tid < 64) { cnt[tid] = 0; cur[tid] = 0; }
  __syncthreads();
  for (int t = tid; t < BIN_CHUNK; t += 256) {
    int d = lde(ei, (size_t)NE + e0 + t, is64);
    atomicAdd(&cnt[d >> 10], 1);
  }
  __syncthreads();
  if (tid < 64 && cnt[tid] > 0) gb[tid] = atomicAdd(&tail[tid], cnt[tid]);
  __syncthreads();
  for (int t = tid; t < BIN_CHUNK; t += 256) {
    int s = lde(ei, (size_t)(e0 + t), is64);
    int d = lde(ei, (size_t)NE + e0 + t, is64);
    int b = d >> 10;
    int r = atomicAdd(&cur[b], 1);
    binned[gb[b] + r] = make_uint2((unsigned)s, (unsigned)d);
  }
}

// Phase B: exact CSR fill from bucket-sorted binned[]; each block's writes are
// confined to a ~65KB dst-window -> L2-resident.
__global__ __launch_bounds__(256) void k_fill2(const uint2* binned, int* fill, int* csr_src) {
  int e = blockIdx.x * 256 + threadIdx.x;
  if (e >= NE) return;
  uint2 u = binned[e];
  int pos = atomicAdd(&fill[u.y], 1);
  csr_src[pos] = (int)u.x;
}

// MFMA GEMM. out = dinv-prescaled bf16 in packed-slot layout:
// row r, u32 slot s in [0,64) holds bf16 pair (col s, col s+64).
// W pre-swizzled bf16 (wp); LDS staging is a raw copy.
// XMODE 0: layer-1 input (probe f32/bf16, row-major).
// XMODE 2: layer-2 input = aggbuf bf16 row-major + fused BN+PReLU (stats).
template <int XMODE>
__global__ __launch_bounds__(256) void k_gemm(const void* in_, const unsigned short* wp,
                                              const int* flags, const float* dinv,
                                              const float* stats, const void* g,
                                              const void* be, const void* al,
                                              unsigned int* out) {
  __shared__ alignas(16) short sW[16 * 128 * 8];  // 32 KB
  __shared__ float sSc[DD], sSh[DD], sAl;
  const int isbf = flags[1];
  const int tid = threadIdx.x;

  {  // raw staged copy, 16B chunks
    const short8* src = (const short8*)wp;
    short8* dst = (short8*)sW;
#pragma unroll
    for (int i = 0; i < 8; i++) dst[tid + i * 256] = src[tid + i * 256];
  }
  if (XMODE == 2) {
    if (tid < DD) {
      const float inv_n = 1.0f / NN;
      float mu = stats[tid] * inv_n;
      float var = stats[DD + tid] * inv_n - mu * mu;
      float sc = rsqrtf(var + BN_EPS) * ldf(g, tid, isbf);
      sSc[tid] = sc;
      sSh[tid] = ldf(be, tid, isbf) - mu * sc;
    }
    if (tid == 0) sAl = ldf(al, 0, isbf);
  }
  __syncthreads();

  const int wave = tid >> 6;
  const int lane = tid & 63;
  const int quad = lane >> 4;
  const int m16 = lane & 15;
  const int r0 = blockIdx.x * 128 + wave * 32;

  f32x4 acc[2][8];
#pragma unroll
  for (int t = 0; t < 2; t++)
#pragma unroll
    for (int n = 0; n < 8; n++) acc[t][n] = (f32x4){0.f, 0.f, 0.f, 0.f};

#pragma unroll
  for (int q = 0; q < 4; q++) {
    const int kq = q * 32 + quad * 8;
    short8 af[2];
#pragma unroll
    for (int t = 0; t < 2; t++) {
      int row = r0 + t * 16 + m16;
      row = row < NN ? row : NN - 1;  // clamp; garbage rows never stored
      if (XMODE == 2) {
        short8 raw = *(const short8*)((const short*)in_ + (size_t)row * DD + kq);
        short8 f;
#pragma unroll
        for (int jj = 0; jj < 8; jj++) {
          float y = s2f(raw[jj]);
          y = y * sSc[kq + jj] + sSh[kq + jj];
          y = y > 0.f ? y : sAl * y;
          f[jj] = (short)f2bs(y);
        }
        af[t] = f;
      } else if (isbf) {
        af[t] = *(const short8*)((const short*)in_ + (size_t)row * DD + kq);
      } else {
        const float* ap = (const float*)in_ + (size_t)row * DD + kq;
        const float4 u0 = *(const float4*)ap;
        const float4 u1 = *(const float4*)(ap + 4);
        float v[8] = {u0.x, u0.y, u0.z, u0.w, u1.x, u1.y, u1.z, u1.w};
        short8 f;
#pragma unroll
        for (int jj = 0; jj < 8; jj++) f[jj] = (short)f2bs(v[jj]);
        af[t] = f;
      }
    }
    const int c = q * 4 + quad;
    const short* bp = sW + c * 1024 + m16 * 8;
#pragma unroll
    for (int n = 0; n < 8; n++) {
      const short8 bfrag = *(const short8*)(bp + n * 128);
      acc[0][n] = __builtin_amdgcn_mfma_f32_16x16x32_bf16(af[0], bfrag, acc[0][n], 0, 0, 0);
      acc[1][n] = __builtin_amdgcn_mfma_f32_16x16x32_bf16(af[1], bfrag, acc[1][n], 0, 0, 0);
    }
  }

  // epilogue: prescale by dinv[row], pack (col, col+64) into one u32 slot
#pragma unroll
  for (int t = 0; t < 2; t++)
#pragma unroll
    for (int r = 0; r < 4; r++) {
      int row = r0 + t * 16 + quad * 4 + r;
      if (row < NN) {
        float di = dinv[row];
        unsigned int* orow = out + (size_t)row * 64;
#pragma unroll
        for (int n = 0; n < 4; n++) {
          unsigned int p = (f2bs(di * acc[t][n + 4][r]) << 16) | f2bs(di * acc[t][n][r]);
          orow[n * 16 + m16] = p;
        }
      }
    }
}

// One wave per node d. hs = dinv-prescaled rows, packed-slot layout.
// agg[d] = dinv[d]*(hs[d] + sum_e hs[s]) + b, written row-major bf16.
// stats_z non-null: block 0 zeroes BN stats (safe: prior consumers finished).
__global__ __launch_bounds__(256) void k_agg(const unsigned int* hs, const float* dinv,
                                             const int* rowptr, const int* csr_src,
                                             const void* bias, const int* flags,
                                             unsigned short* out, float* stats_z) {
  if (stats_z && blockIdx.x == 0) stats_z[threadIdx.x] = 0.f;
  int w = (blockIdx.x * 256 + threadIdx.x) >> 6;
  if (w >= NN) return;
  int lane = threadIdx.x & 63;
  float dd_ = dinv[w];
  unsigned int hv = hs[(size_t)w * 64 + lane];
  float ax = bslo(hv), ay = bshi(hv);
  int e = rowptr[w], e1 = rowptr[w + 1];
  for (; e + 3 < e1; e += 4) {  // 4 row-loads in flight
    int s0 = csr_src[e], s1 = csr_src[e + 1], s2 = csr_src[e + 2], s3 = csr_src[e + 3];
    unsigned int v0 = hs[(size_t)s0 * 64 + lane];
    unsigned int v1 = hs[(size_t)s1 * 64 + lane];
    unsigned int v2 = hs[(size_t)s2 * 64 + lane];
    unsigned int v3 = hs[(size_t)s3 * 64 + lane];
    ax += bslo(v0) + bslo(v1) + bslo(v2) + bslo(v3);
    ay += bshi(v0) + bshi(v1) + bshi(v2) + bshi(v3);
  }
  for (; e < e1; e++) {
    unsigned int v0 = hs[(size_t)csr_src[e] * 64 + lane];
    ax += bslo(v0);
    ay += bshi(v0);
  }
  int isbf = flags[1];
  unsigned short* orow = out + (size_t)w * DD;
  orow[lane] = (unsigned short)f2bs(dd_ * ax + ldf(bias, lane, isbf));
  orow[lane + 64] = (unsigned short)f2bs(dd_ * ay + ldf(bias, lane + 64, isbf));
}

// BN stats over bf16 row-major x: 256 thr, thread t owns col pair (2c, 2c+1),
// c = t&63; rowgroup t>>6 strides rows. LDS-reduce 4 rowgroups -> 4 atomics/col-pair.
__global__ __launch_bounds__(256) void k_bn_stats(const unsigned int* x32, float* stats) {
  __shared__ float rsx[256], rsy[256], rqx[256], rqy[256];
  int t = threadIdx.x;
  int c = t & 63;
  float sx = 0.f, sy = 0.f, qx = 0.f, qy = 0.f;
  for (int r = blockIdx.x * 4 + (t >> 6); r < NN; r += gridDim.x * 4) {
    unsigned int u = x32[(size_t)r * 64 + c];
    float a = bslo(u), b = bshi(u);
    sx += a; qx += a * a;
    sy += b; qy += b * b;
  }
  rsx[t] = sx; rsy[t] = sy; rqx[t] = qx; rqy[t] = qy;
  __syncthreads();
  if (t < 64) {
    sx = rsx[t] + rsx[t + 64] + rsx[t + 128] + rsx[t + 192];
    sy = rsy[t] + rsy[t + 64] + rsy[t + 128] + rsy[t + 192];
    qx = rqx[t] + rqx[t + 64] + rqx[t + 128] + rqx[t + 192];
    qy = rqy[t] + rqy[t + 64] + rqy[t + 128] + rqy[t + 192];
    atomicAdd(&stats[2 * t], sx);
    atomicAdd(&stats[2 * t + 1], sy);
    atomicAdd(&stats[DD + 2 * t], qx);
    atomicAdd(&stats[DD + 2 * t + 1], qy);
  }
}

// Final BN+PReLU: bf16 row-major in -> d_out (f32 unless inputs were bf16).
__global__ __launch_bounds__(256) void k_bn_apply(const unsigned int* x32, const float* stats,
                                                  const void* g, const void* be, const void* al,
                                                  const int* flags, void* out) {
  int i4 = blockIdx.x * 256 + threadIdx.x;  // uint2 (4 cols) granularity
  if (i4 >= NN * 32) return;
  int isbf = flags[1];
  int jq = (i4 & 31) * 4;
  const float inv_n = 1.0f / NN;
  float alpha = ldf(al, 0, isbf);
  const uint2 xv = ((const uint2*)x32)[i4];
  float xa[4] = {bslo(xv.x), bshi(xv.x), bslo(xv.y), bshi(xv.y)};
  float y[4];
#pragma unroll
  for (int u = 0; u < 4; u++) {
    int j = jq + u;
    float mu = stats[j] * inv_n;
    float var = stats[DD + j] * inv_n - mu * mu;
    float sc = rsqrtf(var + BN_EPS) * ldf(g, j, isbf);
    float v = (xa[u] - mu) * sc + ldf(be, j, isbf);
    y[u] = v > 0.f ? v : alpha * v;
  }
  if (isbf) {
    uint2 o;
    o.x = (f2bs(y[1]) << 16) | f2bs(y[0]);
    o.y = (f2bs(y[3]) << 16) | f2bs(y[2]);
    ((uint2*)out)[i4] = o;
  } else {
    float4 o = {y[0], y[1], y[2], y[3]};
    ((float4*)out)[i4] = o;
  }
}

extern "C" void kernel_launch(void* const* d_in, const int* in_sizes, int n_in,
                              void* d_out, int out_size, void* d_ws, size_t ws_size,
                              hipStream_t stream) {
  const void* x = d_in[0];
  const void* ei = d_in[1];
  const void* W1 = d_in[2];
  const void* b1 = d_in[3];
  const void* g1 = d_in[4];
  const void* be1 = d_in[5];
  const void* a1 = d_in[6];
  const void* W2 = d_in[7];
  const void* b2 = d_in[8];
  const void* g2 = d_in[9];
  const void* be2 = d_in[10];
  const void* a2 = d_in[11];

  char* w = (char*)d_ws;
  float* dinv = (float*)w;                              // 200000
  int* flags = (int*)(w + 200704);                      // 8
  float* stats = (float*)(w + 201728);                  // 1024
  int* deg = (int*)(w + 204800);                        // 200000
  int* rowptr = (int*)(w + 404800);                     // 200004
  int* fill = (int*)(w + 604816);                       // 200000
  int* partial = (int*)(w + 804816);                    // 784
  int* tail = (int*)(w + 805632);                       // 256
  int* csr_src = (int*)(w + 1048576);                   // 3200000
  unsigned int* hbuf = (unsigned int*)(w + 4456448);    // 12800000 (packed slots)
  unsigned short* wp1 = (unsigned short*)(w + 17256448);  // 32768
  unsigned short* wp2 = (unsigned short*)(w + 17289216);  // 32768
  unsigned short* aggbuf = (unsigned short*)(w + 30056448);  // 12800000 bf16 row-major
  uint2* binned = (uint2*)(w + 42856448);               // 6400000

  const int NB_N = (NN + 255) / 256;   // 196
  const int NB_E = (NE + 255) / 256;   // 3125
  const int NB_G = (NN + 127) / 128;   // 391
  const int NB_V = NN * 32 / 256;      // 6250 (exact)
  const int NB_W = NN * 64 / 256;      // 12500 (exact)

  k_detect<<<dim3(1), dim3(64), 0, stream>>>((const int*)ei, (const unsigned short*)x, flags);
  k_prep<<<dim3(128), dim3(256), 0, stream>>>(W1, W2, flags, wp1, wp2, stats);

  // CSR build (shared by both layers) + dinv
  k_zero_deg<<<dim3(NB_N), dim3(256), 0, stream>>>(deg);
  k_count_deg<<<dim3(NB_E), dim3(256), 0, stream>>>(ei, flags, deg);
  k_scan1<<<dim3(NB_N), dim3(256), 0, stream>>>(deg, rowptr, partial, dinv);
  k_scan2<<<dim3(1), dim3(256), 0, stream>>>(partial, rowptr);
  k_scan3<<<dim3(NB_N), dim3(256), 0, stream>>>(partial, rowptr, fill, tail);
  k_bin<<<dim3(256), dim3(256), 0, stream>>>(ei, flags, tail, binned);
  k_fill2<<<dim3(NB_E), dim3(256), 0, stream>>>(binned, fill, csr_src);

  // ---- layer 1 ----
  k_gemm<0><<<dim3(NB_G), dim3(256), 0, stream>>>(x, wp1, flags, dinv,
                                                  nullptr, nullptr, nullptr, nullptr, hbuf);
  k_agg<<<dim3(NB_W), dim3(256), 0, stream>>>(hbuf, dinv, rowptr, csr_src, b1, flags,
                                              aggbuf, nullptr);
  k_bn_stats<<<dim3(512), dim3(256), 0, stream>>>((const unsigned int*)aggbuf, stats);

  // ---- layer 2 (BN1+PReLU fused into GEMM A-path) ----
  k_gemm<2><<<dim3(NB_G), dim3(256), 0, stream>>>(aggbuf, wp2, flags, dinv,
                                                  stats, g1, be1, a1, hbuf);
  k_agg<<<dim3(NB_W), dim3(256), 0, stream>>>(hbuf, dinv, rowptr, csr_src, b2, flags,
                                              aggbuf, stats);
  k_bn_stats<<<dim3(512), dim3(256), 0, stream>>>((const unsigned int*)aggbuf, stats);
  k_bn_apply<<<dim3(NB_V), dim3(256), 0, stream>>>((const unsigned int*)aggbuf, stats,
                                                   g2, be2, a2, flags, d_out);
}

// Round 9
// 349.027 us; speedup vs baseline: 9.7641x; 1.0865x over previous
//
#include <hip/hip_runtime.h>
#include <hip/hip_bf16.h>

// 2-layer GCN encoder: (GCNConv -> BatchNorm1d(train) -> PReLU) x 2
// N=50000, E=800000, D=128. Inputs f32 (probed), edge_index int64 (probed),
// output f32. Internal: GEMM/agg buffers bf16, math f32.
//
// R9: (1) k_count_deg (800k random cross-XCD atomic RMW on 200KB) replaced by
//     bucket-count (LDS hist + 64 atomics/block) -> bucket scan -> k_bin ->
//     per-bucket LDS histogram (k_deg: 49 blocks, 4KB LDS, zero global
//     atomics) producing deg+dinv.
//     (2) k_agg: 8-deep edge unroll (8 row-gathers in flight).
//     (3) folds: detect zeroes bucket counters; scan1 drops dinv; scan3 drops
//     tail init.
//
// ws layout (bytes):
//   [0       .. +200000)   dinv f32[NN]
//   [200704  .. +8)        flags: [0]=int64?, [1]=bf16-floats?
//   [201728  .. +1024)     BN stats (sum[128], sumsq[128])
//   [204800  .. +200000)   deg   int[NN]
//   [404800  .. +200004)   rowptr int[NN+1]
//   [604816  .. +200000)   fill  int[NN]
//   [804816  .. +784)      partial int[196]
//   [805632  .. +256)      tail int[64]
//   [805888  .. +256)      bcnt int[64]
//   [806144  .. +260)      bbase int[65]
//   [1048576 .. +3.2MB)    csr_src int[NE]
//   [4456448 .. +12.8MB)   hbuf  bf16[NN*DD] packed-slot layout (dinv-scaled)
//   [17256448.. +32768)    wp1 bf16[128*128] swizzled
//   [17289216.. +32768)    wp2 bf16[128*128] swizzled
//   [30056448.. +12.8MB)   aggbuf bf16[NN*DD] row-major
//   [42856448.. +6.4MB)    binned uint2[NE]
// total ~49.3 MB

typedef __hip_bfloat16 bf16;
typedef __attribute__((ext_vector_type(8))) short short8;   // 8 bf16 = 4 VGPR
typedef __attribute__((ext_vector_type(4))) float f32x4;    // MFMA accumulator

#define NN 50000
#define NE 800000
#define DD 128
#define BN_EPS 1e-5f
#define NB196 196
#define BIN_CHUNK 3125   // NE / 256 exactly

__device__ __forceinline__ float b2f(bf16 v) { return __bfloat162float(v); }
__device__ __forceinline__ float ldf(const void* p, size_t idx, int isbf) {
  return isbf ? b2f(((const bf16*)p)[idx]) : ((const float*)p)[idx];
}
__device__ __forceinline__ int lde(const void* ei, size_t idx, int is64) {
  return is64 ? (int)((const long long*)ei)[idx] : ((const int*)ei)[idx];
}
__device__ __forceinline__ unsigned int f2bs(float v) {
  bf16 b = __float2bfloat16(v);
  return (unsigned int)*reinterpret_cast<unsigned short*>(&b);
}
__device__ __forceinline__ float bslo(unsigned int u) { return __uint_as_float(u << 16); }
__device__ __forceinline__ float bshi(unsigned int u) { return __uint_as_float(u & 0xFFFF0000u); }
__device__ __forceinline__ float s2f(short v) {
  return __uint_as_float(((unsigned int)(unsigned short)v) << 16);
}

// 1 block x 256. Lanes 0-63: dtype probes. Also zeroes bcnt[64].
__global__ void k_detect(const int* ei, const unsigned short* x16, int* flags, int* bcnt) {
  int t = threadIdx.x;
  if (t < 64) bcnt[t] = 0;
  if (t >= 64) return;
  unsigned long long m1 = __ballot(ei[2 * t + 1] != 0);
  int ex = (x16[2 * t] >> 7) & 0xFF;
  unsigned long long m2 = __ballot(ex >= 90 && ex <= 140);
  if (t == 0) {
    flags[0] = (m1 == 0ull) ? 1 : 0;
    flags[1] = (__popcll(m2) >= 48) ? 1 : 0;
  }
}

// Pre-swizzle W1/W2 into bf16 fragment layout: wp[(k>>3)*1024 + n*8 + (k&7)].
// Blocks 0..63 -> W1, 64..127 -> W2. Block 127 also zeroes BN stats.
__global__ __launch_bounds__(256) void k_prep(const void* W1, const void* W2,
                                              const int* flags,
                                              unsigned short* wp1, unsigned short* wp2,
                                              float* stats) {
  const int isbf = flags[1];
  const void* W = blockIdx.x < 64 ? W1 : W2;
  unsigned short* wp = blockIdx.x < 64 ? wp1 : wp2;
  int idx = (blockIdx.x & 63) * 256 + threadIdx.x;
  int k = idx >> 7, n = idx & 127;
  wp[(k >> 3) * 1024 + n * 8 + (k & 7)] = (unsigned short)f2bs(ldf(W, idx, isbf));
  if (blockIdx.x == 127) stats[threadIdx.x] = 0.f;
}

// Bucket-level histogram of dst>>10: LDS counters + 64 global atomics/block.
__global__ __launch_bounds__(256) void k_bcount(const void* ei, const int* flags, int* bcnt) {
  __shared__ int cnt[64];
  const int tid = threadIdx.x;
  if (tid < 64) cnt[tid] = 0;
  __syncthreads();
  const int e0 = blockIdx.x * BIN_CHUNK;
  const int is64 = flags[0];
  for (int t = tid; t < BIN_CHUNK; t += 256) {
    int d = lde(ei, (size_t)NE + e0 + t, is64);
    atomicAdd(&cnt[d >> 10], 1);
  }
  __syncthreads();
  if (tid < 64 && cnt[tid]) atomicAdd(&bcnt[tid], cnt[tid]);
}

// Exclusive scan of bcnt[64] -> bbase[0..64]; also seeds tail[] for k_bin.
__global__ void k_bscan(const int* bcnt, int* bbase, int* tail) {  // 64 thr
  __shared__ int s[64];
  int t = threadIdx.x;
  int v = bcnt[t];
  s[t] = v;
  __syncthreads();
  for (int off = 1; off < 64; off <<= 1) {
    int u = (t >= off) ? s[t - off] : 0;
    __syncthreads();
    s[t] += u;
    __syncthreads();
  }
  int ex = s[t] - v;
  bbase[t] = ex;
  tail[t] = ex;
  if (t == 63) bbase[64] = s[63];  // == NE
}

// Phase A: bin edges by dst-bucket (d>>10, 49 buckets) into binned[] (s,d).
// 256 blocks x 3125 edges. Per-block reserved segments -> L2-coalesced writes.
__global__ __launch_bounds__(256) void k_bin(const void* ei, const int* flags,
                                             int* tail, uint2* binned) {
  __shared__ int cnt[64], cur[64], gb[64];
  const int is64 = flags[0];
  const int tid = threadIdx.x;
  const int e0 = blockIdx.x * BIN_CHUNK;
  if (tid < 64) { cnt[tid] = 0; cur[tid] = 0; }
  __syncthreads();
  for (int t = tid; t < BIN_CHUNK; t += 256) {
    int d = lde(ei, (size_t)NE + e0 + t, is64);
    atomicAdd(&cnt[d >> 10], 1);
  }
  __syncthreads();
  if (tid < 64 && cnt[tid] > 0) gb[tid] = atomicAdd(&tail[tid], cnt[tid]);
  __syncthreads();
  for (int t = tid; t < BIN_CHUNK; t += 256) {
    int s = lde(ei, (size_t)(e0 + t), is64);
    int d = lde(ei, (size_t)NE + e0 + t, is64);
    int b = d >> 10;
    int r = atomicAdd(&cur[b], 1);
    binned[gb[b] + r] = make_uint2((unsigned)s, (unsigned)d);
  }
}

// Per-bucket degree histogram in LDS (zero global atomics) + dinv.
// 49 blocks x 1024 thr; bucket b covers nodes [b*1024, b*1024+1024).
__global__ __launch_bounds__(1024) void k_deg(const uint2* binned, const int* bbase,
                                              int* deg, float* dinv) {
  __shared__ int hist[1024];
  const int b = blockIdx.x;
  const int t = threadIdx.x;
  hist[t] = 0;
  __syncthreads();
  const int e1 = bbase[b + 1];
  for (int e = bbase[b] + t; e < e1; e += 1024)
    atomicAdd(&hist[binned[e].y & 1023], 1);
  __syncthreads();
  int node = b * 1024 + t;
  if (node < NN) {
    int dg = hist[t];
    deg[node] = dg;
    dinv[node] = rsqrtf((float)(dg + 1));  // +1 self-loop
  }
}

// Multi-block exclusive scan of deg -> rowptr (3 stages).
__global__ __launch_bounds__(256) void k_scan1(const int* deg, int* rowptr, int* partial) {
  __shared__ int s[256];
  int i = blockIdx.x * 256 + threadIdx.x;
  int v = (i < NN) ? deg[i] : 0;
  s[threadIdx.x] = v;
  __syncthreads();
  for (int off = 1; off < 256; off <<= 1) {
    int t = (threadIdx.x >= off) ? s[threadIdx.x - off] : 0;
    __syncthreads();
    s[threadIdx.x] += t;
    __syncthreads();
  }
  if (i < NN) rowptr[i] = s[threadIdx.x] - v;  // block-local exclusive
  if (threadIdx.x == 255) partial[blockIdx.x] = s[255];
}

__global__ __launch_bounds__(256) void k_scan2(int* partial, int* rowptr) {
  __shared__ int s[256];
  int v = (threadIdx.x < NB196) ? partial[threadIdx.x] : 0;
  s[threadIdx.x] = v;
  __syncthreads();
  for (int off = 1; off < 256; off <<= 1) {
    int t = (threadIdx.x >= off) ? s[threadIdx.x - off] : 0;
    __syncthreads();
    s[threadIdx.x] += t;
    __syncthreads();
  }
  if (threadIdx.x < NB196) partial[threadIdx.x] = s[threadIdx.x] - v;  // exclusive
  if (threadIdx.x == 255) rowptr[NN] = s[255];  // == NE
}

// Stage 3: add block offsets; init fill[].
__global__ __launch_bounds__(256) void k_scan3(const int* partial, int* rowptr, int* fill) {
  int i = blockIdx.x * 256 + threadIdx.x;
  if (i < NN) {
    int v = rowptr[i] + partial[blockIdx.x];
    rowptr[i] = v;
    fill[i] = v;
  }
}

// Phase B: exact CSR fill from bucket-sorted binned[]; each block's writes are
// confined to a ~65KB dst-window -> L2-resident.
__global__ __launch_bounds__(256) void k_fill2(const uint2* binned, int* fill, int* csr_src) {
  int e = blockIdx.x * 256 + threadIdx.x;
  if (e >= NE) return;
  uint2 u = binned[e];
  int pos = atomicAdd(&fill[u.y], 1);
  csr_src[pos] = (int)u.x;
}

// MFMA GEMM. out = dinv-prescaled bf16 in packed-slot layout:
// row r, u32 slot s in [0,64) holds bf16 pair (col s, col s+64).
// W pre-swizzled bf16 (wp); LDS staging is a raw copy.
// XMODE 0: layer-1 input (probe f32/bf16, row-major).
// XMODE 2: layer-2 input = aggbuf bf16 row-major + fused BN+PReLU (stats).
template <int XMODE>
__global__ __launch_bounds__(256) void k_gemm(const void* in_, const unsigned short* wp,
                                              const int* flags, const float* dinv,
                                              const float* stats, const void* g,
                                              const void* be, const void* al,
                                              unsigned int* out) {
  __shared__ alignas(16) short sW[16 * 128 * 8];  // 32 KB
  __shared__ float sSc[DD], sSh[DD], sAl;
  const int isbf = flags[1];
  const int tid = threadIdx.x;

  {  // raw staged copy, 16B chunks
    const short8* src = (const short8*)wp;
    short8* dst = (short8*)sW;
#pragma unroll
    for (int i = 0; i < 8; i++) dst[tid + i * 256] = src[tid + i * 256];
  }
  if (XMODE == 2) {
    if (tid < DD) {
      const float inv_n = 1.0f / NN;
      float mu = stats[tid] * inv_n;
      float var = stats[DD + tid] * inv_n - mu * mu;
      float sc = rsqrtf(var + BN_EPS) * ldf(g, tid, isbf);
      sSc[tid] = sc;
      sSh[tid] = ldf(be, tid, isbf) - mu * sc;
    }
    if (tid == 0) sAl = ldf(al, 0, isbf);
  }
  __syncthreads();

  const int wave = tid >> 6;
  const int lane = tid & 63;
  const int quad = lane >> 4;
  const int m16 = lane & 15;
  const int r0 = blockIdx.x * 128 + wave * 32;

  f32x4 acc[2][8];
#pragma unroll
  for (int t = 0; t < 2; t++)
#pragma unroll
    for (int n = 0; n < 8; n++) acc[t][n] = (f32x4){0.f, 0.f, 0.f, 0.f};

#pragma unroll
  for (int q = 0; q < 4; q++) {
    const int kq = q * 32 + quad * 8;
    short8 af[2];
#pragma unroll
    for (int t = 0; t < 2; t++) {
      int row = r0 + t * 16 + m16;
      row = row < NN ? row : NN - 1;  // clamp; garbage rows never stored
      if (XMODE == 2) {
        short8 raw = *(const short8*)((const short*)in_ + (size_t)row * DD + kq);
        short8 f;
#pragma unroll
        for (int jj = 0; jj < 8; jj++) {
          float y = s2f(raw[jj]);
          y = y * sSc[kq + jj] + sSh[kq + jj];
          y = y > 0.f ? y : sAl * y;
          f[jj] = (short)f2bs(y);
        }
        af[t] = f;
      } else if (isbf) {
        af[t] = *(const short8*)((const short*)in_ + (size_t)row * DD + kq);
      } else {
        const float* ap = (const float*)in_ + (size_t)row * DD + kq;
        const float4 u0 = *(const float4*)ap;
        const float4 u1 = *(const float4*)(ap + 4);
        float v[8] = {u0.x, u0.y, u0.z, u0.w, u1.x, u1.y, u1.z, u1.w};
        short8 f;
#pragma unroll
        for (int jj = 0; jj < 8; jj++) f[jj] = (short)f2bs(v[jj]);
        af[t] = f;
      }
    }
    const int c = q * 4 + quad;
    const short* bp = sW + c * 1024 + m16 * 8;
#pragma unroll
    for (int n = 0; n < 8; n++) {
      const short8 bfrag = *(const short8*)(bp + n * 128);
      acc[0][n] = __builtin_amdgcn_mfma_f32_16x16x32_bf16(af[0], bfrag, acc[0][n], 0, 0, 0);
      acc[1][n] = __builtin_amdgcn_mfma_f32_16x16x32_bf16(af[1], bfrag, acc[1][n], 0, 0, 0);
    }
  }

  // epilogue: prescale by dinv[row], pack (col, col+64) into one u32 slot
#pragma unroll
  for (int t = 0; t < 2; t++)
#pragma unroll
    for (int r = 0; r < 4; r++) {
      int row = r0 + t * 16 + quad * 4 + r;
      if (row < NN) {
        float di = dinv[row];
        unsigned int* orow = out + (size_t)row * 64;
#pragma unroll
        for (int n = 0; n < 4; n++) {
          unsigned int p = (f2bs(di * acc[t][n + 4][r]) << 16) | f2bs(di * acc[t][n][r]);
          orow[n * 16 + m16] = p;
        }
      }
    }
}

// One wave per node d. hs = dinv-prescaled rows, packed-slot layout.
// agg[d] = dinv[d]*(hs[d] + sum_e hs[s]) + b, written row-major bf16.
// 8-deep unroll: 8 gathered rows in flight.
__global__ __launch_bounds__(256) void k_agg(const unsigned int* hs, const float* dinv,
                                             const int* rowptr, const int* csr_src,
                                             const void* bias, const int* flags,
                                             unsigned short* out, float* stats_z) {
  if (stats_z && blockIdx.x == 0) stats_z[threadIdx.x] = 0.f;
  int w = (blockIdx.x * 256 + threadIdx.x) >> 6;
  if (w >= NN) return;
  int lane = threadIdx.x & 63;
  float dd_ = dinv[w];
  unsigned int hv = hs[(size_t)w * 64 + lane];
  float ax = bslo(hv), ay = bshi(hv);
  int e = rowptr[w], e1 = rowptr[w + 1];
  for (; e + 7 < e1; e += 8) {
    int s0 = csr_src[e], s1 = csr_src[e + 1], s2 = csr_src[e + 2], s3 = csr_src[e + 3];
    int s4 = csr_src[e + 4], s5 = csr_src[e + 5], s6 = csr_src[e + 6], s7 = csr_src[e + 7];
    unsigned int v0 = hs[(size_t)s0 * 64 + lane];
    unsigned int v1 = hs[(size_t)s1 * 64 + lane];
    unsigned int v2 = hs[(size_t)s2 * 64 + lane];
    unsigned int v3 = hs[(size_t)s3 * 64 + lane];
    unsigned int v4 = hs[(size_t)s4 * 64 + lane];
    unsigned int v5 = hs[(size_t)s5 * 64 + lane];
    unsigned int v6 = hs[(size_t)s6 * 64 + lane];
    unsigned int v7 = hs[(size_t)s7 * 64 + lane];
    ax += bslo(v0) + bslo(v1) + bslo(v2) + bslo(v3) + bslo(v4) + bslo(v5) + bslo(v6) + bslo(v7);
    ay += bshi(v0) + bshi(v1) + bshi(v2) + bshi(v3) + bshi(v4) + bshi(v5) + bshi(v6) + bshi(v7);
  }
  for (; e + 3 < e1; e += 4) {
    int s0 = csr_src[e], s1 = csr_src[e + 1], s2 = csr_src[e + 2], s3 = csr_src[e + 3];
    unsigned int v0 = hs[(size_t)s0 * 64 + lane];
    unsigned int v1 = hs[(size_t)s1 * 64 + lane];
    unsigned int v2 = hs[(size_t)s2 * 64 + lane];
    unsigned int v3 = hs[(size_t)s3 * 64 + lane];
    ax += bslo(v0) + bslo(v1) + bslo(v2) + bslo(v3);
    ay += bshi(v0) + bshi(v1) + bshi(v2) + bshi(v3);
  }
  for (; e < e1; e++) {
    unsigned int v0 = hs[(size_t)csr_src[e] * 64 + lane];
    ax += bslo(v0);
    ay += bshi(v0);
  }
  int isbf = flags[1];
  unsigned short* orow = out + (size_t)w * DD;
  orow[lane] = (unsigned short)f2bs(dd_ * ax + ldf(bias, lane, isbf));
  orow[lane + 64] = (unsigned short)f2bs(dd_ * ay + ldf(bias, lane + 64, isbf));
}

// BN stats over bf16 row-major x: thread t owns col pair (2c,2c+1), c=t&63;
// rowgroup t>>6 strides rows. LDS-reduce -> 4 atomics/col-pair.
__global__ __launch_bounds__(256) void k_bn_stats(const unsigned int* x32, float* stats) {
  __shared__ float rsx[256], rsy[256], rqx[256], rqy[256];
  int t = threadIdx.x;
  int c = t & 63;
  float sx = 0.f, sy = 0.f, qx = 0.f, qy = 0.f;
  for (int r = blockIdx.x * 4 + (t >> 6); r < NN; r += gridDim.x * 4) {
    unsigned int u = x32[(size_t)r * 64 + c];
    float a = bslo(u), b = bshi(u);
    sx += a; qx += a * a;
    sy += b; qy += b * b;
  }
  rsx[t] = sx; rsy[t] = sy; rqx[t] = qx; rqy[t] = qy;
  __syncthreads();
  if (t < 64) {
    sx = rsx[t] + rsx[t + 64] + rsx[t + 128] + rsx[t + 192];
    sy = rsy[t] + rsy[t + 64] + rsy[t + 128] + rsy[t + 192];
    qx = rqx[t] + rqx[t + 64] + rqx[t + 128] + rqx[t + 192];
    qy = rqy[t] + rqy[t + 64] + rqy[t + 128] + rqy[t + 192];
    atomicAdd(&stats[2 * t], sx);
    atomicAdd(&stats[2 * t + 1], sy);
    atomicAdd(&stats[DD + 2 * t], qx);
    atomicAdd(&stats[DD + 2 * t + 1], qy);
  }
}

// Final BN+PReLU: bf16 row-major in -> d_out (f32 unless inputs were bf16).
__global__ __launch_bounds__(256) void k_bn_apply(const unsigned int* x32, const float* stats,
                                                  const void* g, const void* be, const void* al,
                                                  const int* flags, void* out) {
  int i4 = blockIdx.x * 256 + threadIdx.x;  // uint2 (4 cols) granularity
  if (i4 >= NN * 32) return;
  int isbf = flags[1];
  int jq = (i4 & 31) * 4;
  const float inv_n = 1.0f / NN;
  float alpha = ldf(al, 0, isbf);
  const uint2 xv = ((const uint2*)x32)[i4];
  float xa[4] = {bslo(xv.x), bshi(xv.x), bslo(xv.y), bshi(xv.y)};
  float y[4];
#pragma unroll
  for (int u = 0; u < 4; u++) {
    int j = jq + u;
    float mu = stats[j] * inv_n;
    float var = stats[DD + j] * inv_n - mu * mu;
    float sc = rsqrtf(var + BN_EPS) * ldf(g, j, isbf);
    float v = (xa[u] - mu) * sc + ldf(be, j, isbf);
    y[u] = v > 0.f ? v : alpha * v;
  }
  if (isbf) {
    uint2 o;
    o.x = (f2bs(y[1]) << 16) | f2bs(y[0]);
    o.y = (f2bs(y[3]) << 16) | f2bs(y[2]);
    ((uint2*)out)[i4] = o;
  } else {
    float4 o = {y[0], y[1], y[2], y[3]};
    ((float4*)out)[i4] = o;
  }
}

extern "C" void kernel_launch(void* const* d_in, const int* in_sizes, int n_in,
                              void* d_out, int out_size, void* d_ws, size_t ws_size,
                              hipStream_t stream) {
  const void* x = d_in[0];
  const void* ei = d_in[1];
  const void* W1 = d_in[2];
  const void* b1 = d_in[3];
  const void* g1 = d_in[4];
  const void* be1 = d_in[5];
  const void* a1 = d_in[6];
  const void* W2 = d_in[7];
  const void* b2 = d_in[8];
  const void* g2 = d_in[9];
  const void* be2 = d_in[10];
  const void* a2 = d_in[11];

  char* w = (char*)d_ws;
  float* dinv = (float*)w;                              // 200000
  int* flags = (int*)(w + 200704);                      // 8
  float* stats = (float*)(w + 201728);                  // 1024
  int* deg = (int*)(w + 204800);                        // 200000
  int* rowptr = (int*)(w + 404800);                     // 200004
  int* fill = (int*)(w + 604816);                       // 200000
  int* partial = (int*)(w + 804816);                    // 784
  int* tail = (int*)(w + 805632);                       // 256
  int* bcnt = (int*)(w + 805888);                       // 256
  int* bbase = (int*)(w + 806144);                      // 260
  int* csr_src = (int*)(w + 1048576);                   // 3200000
  unsigned int* hbuf = (unsigned int*)(w + 4456448);    // 12800000 (packed slots)
  unsigned short* wp1 = (unsigned short*)(w + 17256448);  // 32768
  unsigned short* wp2 = (unsigned short*)(w + 17289216);  // 32768
  unsigned short* aggbuf = (unsigned short*)(w + 30056448);  // 12800000 bf16 row-major
  uint2* binned = (uint2*)(w + 42856448);               // 6400000

  const int NB_N = (NN + 255) / 256;   // 196
  const int NB_E = (NE + 255) / 256;   // 3125
  const int NB_G = (NN + 127) / 128;   // 391
  const int NB_V = NN * 32 / 256;      // 6250 (exact)
  const int NB_W = NN * 64 / 256;      // 12500 (exact)

  k_detect<<<dim3(1), dim3(256), 0, stream>>>((const int*)ei, (const unsigned short*)x,
                                              flags, bcnt);
  k_prep<<<dim3(128), dim3(256), 0, stream>>>(W1, W2, flags, wp1, wp2, stats);

  // CSR build (shared by both layers): bucket-count -> scan -> bin -> deg ->
  // rowptr scans -> exact fill
  k_bcount<<<dim3(256), dim3(256), 0, stream>>>(ei, flags, bcnt);
  k_bscan<<<dim3(1), dim3(64), 0, stream>>>(bcnt, bbase, tail);
  k_bin<<<dim3(256), dim3(256), 0, stream>>>(ei, flags, tail, binned);
  k_deg<<<dim3(49), dim3(1024), 0, stream>>>(binned, bbase, deg, dinv);
  k_scan1<<<dim3(NB_N), dim3(256), 0, stream>>>(deg, rowptr, partial);
  k_scan2<<<dim3(1), dim3(256), 0, stream>>>(partial, rowptr);
  k_scan3<<<dim3(NB_N), dim3(256), 0, stream>>>(partial, rowptr, fill);
  k_fill2<<<dim3(NB_E), dim3(256), 0, stream>>>(binned, fill, csr_src);

  // ---- layer 1 ----
  k_gemm<0><<<dim3(NB_G), dim3(256), 0, stream>>>(x, wp1, flags, dinv,
                                                  nullptr, nullptr, nullptr, nullptr, hbuf);
  k_agg<<<dim3(NB_W), dim3(256), 0, stream>>>(hbuf, dinv, rowptr, csr_src, b1, flags,
                                              aggbuf, nullptr);
  k_bn_stats<<<dim3(512), dim3(256), 0, stream>>>((const unsigned int*)aggbuf, stats);

  // ---- layer 2 (BN1+PReLU fused into GEMM A-path) ----
  k_gemm<2><<<dim3(NB_G), dim3(256), 0, stream>>>(aggbuf, wp2, flags, dinv,
                                                  stats, g1, be1, a1, hbuf);
  k_agg<<<dim3(NB_W), dim3(256), 0, stream>>>(hbuf, dinv, rowptr, csr_src, b2, flags,
                                              aggbuf, stats);
  k_bn_stats<<<dim3(512), dim3(256), 0, stream>>>((const unsigned int*)aggbuf, stats);
  k_bn_apply<<<dim3(NB_V), dim3(256), 0, stream>>>((const unsigned int*)aggbuf, stats,
                                                   g2, be2, a2, flags, d_out);
}